// Round 2
// baseline (695.181 us; speedup 1.0000x reference)
//
#include <hip/hip_runtime.h>
#include <hip/hip_bf16.h>
#include <math.h>

#define NH 8
#define DKk 256
#define DVv 512
#define Bn 2
#define Tn 2048
#define HID 2048
#define EPSf 1e-5f

typedef __bf16 bf16x8 __attribute__((ext_vector_type(8)));
typedef float f32x4 __attribute__((ext_vector_type(4)));
typedef unsigned short us8 __attribute__((ext_vector_type(8)));
using bf16 = __hip_bfloat16;
typedef unsigned short ushort_t;

__device__ __forceinline__ void gload_lds16(const void* g, void* lds_base) {
  __builtin_amdgcn_global_load_lds(
      (const __attribute__((address_space(1))) void*)g,
      (__attribute__((address_space(3))) void*)lds_base, 16, 0, 0);
}

__device__ __forceinline__ ushort_t f2bf_raw(float f) {
  bf16 h = __float2bfloat16(f);
  return *reinterpret_cast<ushort_t*>(&h);
}
__device__ __forceinline__ float bf2f_raw(ushort_t u) {
  union { unsigned int i; float f; } v; v.i = ((unsigned int)u) << 16; return v.f;
}

// ---------------- fp32 -> bf16 elementwise (vectorized x4) ----------------
__global__ void k_f32_to_bf16(const float4* __restrict__ in, ushort4* __restrict__ out, int n4) {
  int i = blockIdx.x * blockDim.x + threadIdx.x;
  if (i >= n4) return;
  float4 v = in[i];
  ushort4 o;
  o.x = f2bf_raw(v.x); o.y = f2bf_raw(v.y); o.z = f2bf_raw(v.z); o.w = f2bf_raw(v.w);
  out[i] = o;
}

// ---------------- W (K,N) fp32 -> WT (N,K) bf16 ----------------
__global__ void k_transpose_w(const float* __restrict__ W, bf16* __restrict__ WT, int K, int N) {
  __shared__ float t[32][33];
  int n0 = blockIdx.x * 32, k0 = blockIdx.y * 32;
  int tx = threadIdx.x, ty = threadIdx.y;
#pragma unroll
  for (int i = 0; i < 4; i++)
    t[ty + i * 8][tx] = W[(size_t)(k0 + ty + i * 8) * N + n0 + tx];
  __syncthreads();
#pragma unroll
  for (int i = 0; i < 4; i++)
    WT[(size_t)(n0 + ty + i * 8) * K + k0 + tx] = __float2bfloat16(t[tx][ty + i * 8]);
}

// ---------------- v (b,t,h,dv) bf16 -> vS[bh][kt][chunk(4)][dv(512)] 16B units ----------------
__global__ void k_build_vS(const ushort_t* __restrict__ v, ushort_t* __restrict__ vS) {
  __shared__ ushort_t t[32 * 520];
  const int tid = threadIdx.x;
  const int kt = blockIdx.x;
  const int bh = blockIdx.y;
  const int b = bh >> 3, h = bh & 7;
#pragma unroll
  for (int r = 0; r < 8; r++) {
    int j = r * 4 + (tid >> 6);
    int vec = tid & 63;
    us8 d = *(const us8*)(v + (((size_t)(b * Tn + kt * 32 + j) * NH + h) * DVv) + vec * 8);
    *(us8*)(&t[j * 520 + vec * 8]) = d;
  }
  __syncthreads();
#pragma unroll
  for (int u = 0; u < 8; u++) {
    int uid = u * 256 + tid;
    int chunk = uid >> 9;
    int dv = uid & 511;
    us8 o;
#pragma unroll
    for (int jj = 0; jj < 8; jj++) o[jj] = t[(chunk * 8 + jj) * 520 + dv];
    *(us8*)(vS + ((size_t)(bh * 64 + kt) * 2048 + chunk * 512 + dv) * 8) = o;
  }
}

// ---------------- RoPE in-place on bf16 (b,t,h,dk), scale folded ----------------
__global__ void k_rope(bf16* __restrict__ x, float scale) {
  int tid = blockIdx.x * 256 + threadIdx.x;
  int i = tid & 127;
  int h = (tid >> 7) & 7;
  int t = (tid >> 10) & (Tn - 1);
  int b = tid >> 21;
  float inv = exp2f(-(float)i * (13.287712379549449f / 128.0f));
  float ang = (float)t * inv;
  float s, c;
  sincosf(ang, &s, &c);
  size_t base = ((size_t)(b * Tn + t) * NH + h) * DKk + i;
  float x1 = __bfloat162float(x[base]);
  float x2 = __bfloat162float(x[base + 128]);
  x[base]       = __float2bfloat16((x1 * c - x2 * s) * scale);
  x[base + 128] = __float2bfloat16((x2 * c + x1 * s) * scale);
}

// ---------------- m97-style GEMM (out-proj) + XCD y-major chunk swizzle ----------------
template <bool OUT_BF16>
__global__ __launch_bounds__(256) void k_gemm(const bf16* __restrict__ A, const bf16* __restrict__ BT,
                                              void* __restrict__ Cout, int M, int N, int K) {
  __shared__ __align__(16) bf16 a_lds[128 * 32];
  __shared__ __align__(16) bf16 b_lds[128 * 32];
  const int tid = threadIdx.x;
  const int l = tid & 63;
  const int w = tid >> 6;
  const int wr = w >> 1, wc = w & 1;
  // XCD swizzle: chunk of nwg/8 consecutive slots per XCD, y-major within chunk
  const int bid = blockIdx.y * gridDim.x + blockIdx.x;
  const int cpx = (gridDim.x * gridDim.y) >> 3;
  const int s = (bid & 7) * cpx + (bid >> 3);
  const int bx = s / gridDim.y, by = s % gridDim.y;
  const int m0 = by * 128, n0 = bx * 128;
  const int quad = l >> 4, c16 = l & 15;

  const int lrow = l >> 2;
  const int loff = (l & 3) * 16;
  const char* aG0 = (const char*)(A + (size_t)(m0 + w * 32 + lrow) * K) + loff;
  const char* aG1 = (const char*)(A + (size_t)(m0 + w * 32 + 16 + lrow) * K) + loff;
  const char* bG0 = (const char*)(BT + (size_t)(n0 + w * 32 + lrow) * K) + loff;
  const char* bG1 = (const char*)(BT + (size_t)(n0 + w * 32 + 16 + lrow) * K) + loff;
  char* aL0 = (char*)a_lds + w * 2048;
  char* aL1 = (char*)a_lds + w * 2048 + 1024;
  char* bL0 = (char*)b_lds + w * 2048;
  char* bL1 = (char*)b_lds + w * 2048 + 1024;

  f32x4 acc[4][4];
  const f32x4 fz = {0.f, 0.f, 0.f, 0.f};
#pragma unroll
  for (int r = 0; r < 4; r++)
#pragma unroll
    for (int c = 0; c < 4; c++) acc[r][c] = fz;

  for (int k0 = 0; k0 < K; k0 += 32) {
    __syncthreads();
    size_t kb = (size_t)k0 * 2;
    gload_lds16(aG0 + kb, aL0);
    gload_lds16(aG1 + kb, aL1);
    gload_lds16(bG0 + kb, bL0);
    gload_lds16(bG1 + kb, bL1);
    __syncthreads();
    bf16x8 af[4], bfv[4];
#pragma unroll
    for (int r = 0; r < 4; r++)
      af[r] = *(const bf16x8*)(a_lds + (wr * 64 + r * 16 + c16) * 32 + quad * 8);
#pragma unroll
    for (int c = 0; c < 4; c++)
      bfv[c] = *(const bf16x8*)(b_lds + (wc * 64 + c * 16 + c16) * 32 + quad * 8);
#pragma unroll
    for (int r = 0; r < 4; r++)
#pragma unroll
      for (int c = 0; c < 4; c++)
        acc[r][c] = __builtin_amdgcn_mfma_f32_16x16x32_bf16(af[r], bfv[c], acc[r][c], 0, 0, 0);
  }

#pragma unroll
  for (int r = 0; r < 4; r++)
#pragma unroll
    for (int c = 0; c < 4; c++)
#pragma unroll
      for (int rr = 0; rr < 4; rr++) {
        int m = m0 + wr * 64 + r * 16 + quad * 4 + rr;
        int n = n0 + wc * 64 + c * 16 + c16;
        float val = acc[r][c][rr];
        if (OUT_BF16) ((bf16*)Cout)[(size_t)m * N + n] = __float2bfloat16(val);
        else          ((float*)Cout)[(size_t)m * N + n] = val;
      }
}

// ================= 256x256 8-phase GEMM, v2 schedule (4-phase slack) =================
// Reads consume a whole buffer in its first 2 phases (ph1/2 for buf0, ph5/6 for buf1),
// so the buffer frees early. Stage BOTH next-iteration tiles at ph3/4/7/8 (2 half-tiles
// per phase):  ph3:(t+2)A  ph4:(t+2)B  ph7:(t+3)A  ph8:(t+3)B.
// Waits: vmcnt(8) at end ph4 (drains (t+1)AB, staged prev ph7/8 -> 4-phase slack) and
// end ph8 (drains (t+2)AB, staged ph3/4 -> 4-phase slack). Never 0 in main loop.
// Ledger: steady-state outstanding enters each iter at 8 ((t+1)AB); ph3 +4, ph4 +4 ->16,
// vmcnt(8) drains 8 oldest == (t+1)AB exactly; ph7/8 symmetric for (t+2)AB.
// Stage-safety: buf0 fully lgkm-drained by all waves before ph2's closing barrier ->
// ph3/4 writes safe; buf1 likewise before ph6's closing barrier -> ph7/8 safe.
#define BARX() asm volatile("s_barrier" ::: "memory")
#define LGKM0() { asm volatile("s_waitcnt lgkmcnt(0)" ::: "memory"); __builtin_amdgcn_sched_barrier(0); }
#define VMW8() asm volatile("s_waitcnt vmcnt(8)" ::: "memory")
#define VMW0() asm volatile("s_waitcnt vmcnt(0)" ::: "memory")
#define PRIO1 __builtin_amdgcn_s_setprio(1)
#define PRIO0 __builtin_amdgcn_s_setprio(0)

#define QUADX(MH, NHh)                                                             \
  { _Pragma("unroll") for (int kk_ = 0; kk_ < 2; ++kk_)                            \
    _Pragma("unroll") for (int mf_ = 0; mf_ < 4; ++mf_)                            \
    _Pragma("unroll") for (int nf_ = 0; nf_ < 2; ++nf_)                            \
      acc[(MH)*4 + mf_][(NHh)*2 + nf_] = __builtin_amdgcn_mfma_f32_16x16x32_bf16(  \
          ar[(MH)*4 + mf_][kk_], br[(NHh)*2 + nf_][kk_],                           \
          acc[(MH)*4 + mf_][(NHh)*2 + nf_], 0, 0, 0); }

__global__ __launch_bounds__(512, 2) void k_gemm8(const bf16* __restrict__ A, const bf16* __restrict__ BT,
                                                  bf16* __restrict__ O0, bf16* __restrict__ O1,
                                                  int nsplit, int M, int Ntot, int K) {
  extern __shared__ char lds[];
  const int tid = threadIdx.x;
  const int lane = tid & 63;
  const int w = tid >> 6;        // 0..7
  const int wr = w >> 2;         // 0..1 (M half)
  const int wc = w & 3;          // 0..3 (N quarter)
  const int quad = lane >> 4, c16 = lane & 15;
  // XCD swizzle: y-major chunks -> each XCD covers few N-columns (B panels L2-fit)
  const int bid = blockIdx.y * gridDim.x + blockIdx.x;
  const int cpx = (gridDim.x * gridDim.y) >> 3;
  const int sw = (bid & 7) * cpx + (bid >> 3);
  const int bx = sw / gridDim.y, by = sw % gridDim.y;
  const int m0 = by * 256, n0 = bx * 256;

  const int srow = (w << 4) | (lane >> 3);
  const int gsw = (((lane & 7) ^ (lane >> 3)) << 4);   // inverse-swizzled source granule
  const size_t rowBytes = (size_t)K * 2;
  const char* aS = (const char*)(A + (size_t)(m0 + srow) * K) + gsw;
  const char* bS = (const char*)(BT + (size_t)(n0 + srow) * K) + gsw;

  auto stage = [&](int matB, int buf, int h, int t) {
    const char* base = (matB ? bS : aS) + (size_t)h * 128 * rowBytes + (size_t)t * 128;
    char* ldst = lds + buf * 65536 + matB * 32768 + h * 16384 + w * 2048;
    gload_lds16(base, ldst);
    gload_lds16(base + 8 * rowBytes, ldst + 1024);
  };
  auto ldA = [&](int buf, int mf, int kk) -> bf16x8 {
    int row = wr * 128 + mf * 16 + c16;
    return *(const bf16x8*)(lds + buf * 65536 + row * 128 + ((((kk << 2) | quad) ^ (c16 & 7)) << 4));
  };
  auto ldB = [&](int buf, int nf, int kk) -> bf16x8 {
    int row = wc * 64 + nf * 16 + c16;
    return *(const bf16x8*)(lds + buf * 65536 + 32768 + row * 128 + ((((kk << 2) | quad) ^ (c16 & 7)) << 4));
  };

  f32x4 acc[8][4];
  const f32x4 fz = {0.f, 0.f, 0.f, 0.f};
#pragma unroll
  for (int i = 0; i < 8; i++)
#pragma unroll
    for (int j = 0; j < 4; j++) acc[i][j] = fz;
  bf16x8 ar[8][2], br[4][2];

  const int nT = K >> 6;
  const int nIter = nT >> 1;

  // prologue: tiles 0 and 1 fully staged (16 loads); vmcnt(8) -> tile0 landed, tile1 in flight
  stage(0, 0, 0, 0); stage(0, 0, 1, 0);
  stage(1, 0, 0, 0); stage(1, 0, 1, 0);
  stage(0, 1, 0, 1); stage(0, 1, 1, 1);
  stage(1, 1, 0, 1); stage(1, 1, 1, 1);
  VMW8();
  BARX();

  for (int it = 0; it < nIter; ++it) {
    const int t = it * 2;
    const bool last = (it == nIter - 1);
    // ---- ph1: read buf0 A[0..3],B[0..1] ----
#pragma unroll
    for (int mf = 0; mf < 4; ++mf) { ar[mf][0] = ldA(0, mf, 0); ar[mf][1] = ldA(0, mf, 1); }
#pragma unroll
    for (int nf = 0; nf < 2; ++nf) { br[nf][0] = ldB(0, nf, 0); br[nf][1] = ldB(0, nf, 1); }
    BARX(); LGKM0();
    PRIO1; QUADX(0, 0); PRIO0;
    BARX();
    // ---- ph2: read buf0 A[4..7],B[2..3] ----
#pragma unroll
    for (int mf = 4; mf < 8; ++mf) { ar[mf][0] = ldA(0, mf, 0); ar[mf][1] = ldA(0, mf, 1); }
#pragma unroll
    for (int nf = 2; nf < 4; ++nf) { br[nf][0] = ldB(0, nf, 0); br[nf][1] = ldB(0, nf, 1); }
    BARX(); LGKM0();
    PRIO1; QUADX(0, 1); PRIO0;
    BARX();
    // ---- ph3: stage (t+2)A (buf0.A fully read) ----
    if (!last) { stage(0, 0, 0, t + 2); stage(0, 0, 1, t + 2); }
    BARX();
    PRIO1; QUADX(1, 0); PRIO0;
    BARX();
    // ---- ph4: stage (t+2)B; counted wait -> tile t+1 landed ----
    if (!last) { stage(1, 0, 0, t + 2); stage(1, 0, 1, t + 2); }
    BARX();
    PRIO1; QUADX(1, 1); PRIO0;
    if (!last) { VMW8(); } else { VMW0(); }
    BARX();
    // ---- ph5: read buf1 A[0..3],B[0..1] ----
#pragma unroll
    for (int mf = 0; mf < 4; ++mf) { ar[mf][0] = ldA(1, mf, 0); ar[mf][1] = ldA(1, mf, 1); }
#pragma unroll
    for (int nf = 0; nf < 2; ++nf) { br[nf][0] = ldB(1, nf, 0); br[nf][1] = ldB(1, nf, 1); }
    BARX(); LGKM0();
    PRIO1; QUADX(0, 0); PRIO0;
    BARX();
    // ---- ph6: read buf1 A[4..7],B[2..3] ----
#pragma unroll
    for (int mf = 4; mf < 8; ++mf) { ar[mf][0] = ldA(1, mf, 0); ar[mf][1] = ldA(1, mf, 1); }
#pragma unroll
    for (int nf = 2; nf < 4; ++nf) { br[nf][0] = ldB(1, nf, 0); br[nf][1] = ldB(1, nf, 1); }
    BARX(); LGKM0();
    PRIO1; QUADX(0, 1); PRIO0;
    BARX();
    // ---- ph7: stage (t+3)A (buf1 fully read) ----
    if (!last) { stage(0, 1, 0, t + 3); stage(0, 1, 1, t + 3); }
    BARX();
    PRIO1; QUADX(1, 0); PRIO0;
    BARX();
    // ---- ph8: stage (t+3)B; counted wait -> tile t+2 landed ----
    if (!last) { stage(1, 1, 0, t + 3); stage(1, 1, 1, t + 3); }
    BARX();
    PRIO1; QUADX(1, 1); PRIO0;
    if (!last) VMW8();
    BARX();
  }

  // epilogue: whole block routes to one output (BN=256 divides nsplit)
  bf16* Ob; int ldo, nc0;
  if (n0 < nsplit) { Ob = O0; ldo = nsplit; nc0 = n0; }
  else             { Ob = O1; ldo = Ntot - nsplit; nc0 = n0 - nsplit; }
#pragma unroll
  for (int mf = 0; mf < 8; ++mf)
#pragma unroll
    for (int nf = 0; nf < 4; ++nf)
#pragma unroll
      for (int rr = 0; rr < 4; ++rr) {
        int m = m0 + wr * 128 + mf * 16 + quad * 4 + rr;
        int n = nc0 + wc * 64 + nf * 16 + c16;
        Ob[(size_t)m * ldo + n] = __float2bfloat16(acc[mf][nf][rr]);
      }
}

// ---------------- Retention v2: K double-buffered, V read direct from global ----------------
// V-staging had ZERO intra-block reuse (each V byte consumed once) -> dropped (guide CM#7);
// bv fragments read straight from vS (L2/L3-resident), killing the 8-way LDS conflict.
// K(t+1) staged at loop top into other buffer; drained by NEXT iteration's __syncthreads
// (full-iteration overlap). Mid-iteration barrier is lgkm-only so K loads stay in flight.
__global__ __launch_bounds__(256, 2) void k_retention(const bf16* __restrict__ q, const bf16* __restrict__ k,
                                                      const char* __restrict__ vS, const bf16* __restrict__ g,
                                                      const float* __restrict__ gnw, bf16* __restrict__ X) {
  __shared__ __align__(16) char smem[65536];
  // loop layout: K dbuf [2][16KB] @0; p_lds @32768 (64 rows x 40 ushorts = 5120B); red @38912 (1KB)
  ushort_t* p_lds = (ushort_t*)(smem + 32768);
  float* red = (float*)(smem + 38912);
  bf16* o_lds = (bf16*)smem;   // epilogue, aliases everything (after full sync)

  const int tid = threadIdx.x;
  const int l = tid & 63, w = tid >> 6;
  const int quad = l >> 4, c16 = l & 15;

  const int bid = blockIdx.x;
  const int xcd = bid & 7;
  const int slot = bid >> 3;
  const int bh = xcd + 8 * (slot & 1);
  const int b = bh >> 3, h = bh & 7;
  const int qt = 31 - (slot >> 1);
  const int q0 = qt * 64;

  bf16x8 qf[8];
  {
    const bf16* qrow = q + ((size_t)(b * Tn + q0 + w * 16 + c16) * NH + h) * DKk + quad * 8;
#pragma unroll
    for (int c = 0; c < 8; c++) qf[c] = *(const bf16x8*)(qrow + c * 32);
  }

  const float log2g = log2f(1.0f - exp2f(-5.0f - (float)h));

  f32x4 acc[4][8];
  const f32x4 fz = {0.f, 0.f, 0.f, 0.f};
#pragma unroll
  for (int rt = 0; rt < 4; rt++)
#pragma unroll
    for (int n = 0; n < 8; n++) acc[rt][n] = fz;

  const int ktmax = 2 * qt + 1;
  const float Dcut = 30.0f / (-log2g);
  int kt0 = (int)fmaxf(0.0f, floorf(((float)q0 - Dcut) * (1.0f / 32.0f)));

  const char* vS_tilebase = vS + (size_t)(bh * 64) * 32768;

  auto stageK = [&](int kt, int pbuf) {
#pragma unroll
    for (int i = 0; i < 4; i++) {
      int instr = w * 4 + i;
      int j = instr * 2 + (l >> 5);
      int chunk_g = (l & 31) ^ (j & 7);
      const char* gp = (const char*)(k + ((size_t)(b * Tn + kt * 32 + j) * NH + h) * DKk) + chunk_g * 16;
      gload_lds16(gp, smem + pbuf * 16384 + instr * 1024);
    }
  };

  stageK(kt0, 0);

  for (int kt = kt0; kt <= ktmax; kt++) {
    const int pb = (kt - kt0) & 1;
    __syncthreads();   // drains vmcnt(0): K(kt) landed; also p_lds/prev-buf reads all done
    if (kt < ktmax) stageK(kt + 1, pb ^ 1);   // in flight across this whole iteration

    // S: wave's 16 rows x 32 j (2 j-tiles), K from LDS buf pb
    f32x4 sacc[2] = {fz, fz};
#pragma unroll
    for (int jt = 0; jt < 2; jt++)
#pragma unroll
      for (int c = 0; c < 8; c++) {
        const char* kp = smem + pb * 16384 + (jt * 16 + c16) * 512 + (((c * 4 + quad) ^ (c16 & 7)) * 16);
        bf16x8 bfrag = *(const bf16x8*)kp;
        sacc[jt] = __builtin_amdgcn_mfma_f32_16x16x32_bf16(qf[c], bfrag, sacc[jt], 0, 0, 0);
      }

    // decay + causal mask -> P (bf16) in padded LDS
#pragma unroll
    for (int jt = 0; jt < 2; jt++)
#pragma unroll
      for (int r = 0; r < 4; r++) {
        int ig = q0 + w * 16 + quad * 4 + r;
        int jg = kt * 32 + jt * 16 + c16;
        int d = ig - jg;
        float val = (d >= 0) ? sacc[jt][r] * exp2f(log2g * (float)d) : 0.0f;
        p_lds[(w * 16 + quad * 4 + r) * 40 + jt * 16 + c16] = f2bf_raw(val);
      }
    // lgkm-only barrier: p_lds visible; K(kt+1) gload_lds stays in flight (vmcnt untouched)
    asm volatile("s_waitcnt lgkmcnt(0)" ::: "memory");
    __builtin_amdgcn_sched_barrier(0);
    __builtin_amdgcn_s_barrier();

    // O += P @ V : bv direct from global vS (L2/L3), wave w covers dv = w*128..+127
    bf16x8 pa[4];
#pragma unroll
    for (int rt = 0; rt < 4; rt++)
      pa[rt] = *(const bf16x8*)((const char*)p_lds + (rt * 16 + c16) * 80 + quad * 16);
    const char* vt = vS_tilebase + (size_t)kt * 32768 + quad * 8192 + w * 2048 + c16 * 16;
#pragma unroll
    for (int n = 0; n < 8; n++) {
      bf16x8 bv = *(const bf16x8*)(vt + n * 256);
#pragma unroll
      for (int rt = 0; rt < 4; rt++)
        acc[rt][n] = __builtin_amdgcn_mfma_f32_16x16x32_bf16(pa[rt], bv, acc[rt][n], 0, 0, 0);
    }
  }

  // RMS: wave has 128-dv partial for all 64 rows -> cross-wave combine via red
  __syncthreads();
#pragma unroll
  for (int rt = 0; rt < 4; rt++)
#pragma unroll
    for (int r = 0; r < 4; r++) {
      float s = 0.f;
#pragma unroll
      for (int n = 0; n < 8; n++) { float v = acc[rt][n][r]; s += v * v; }
      s += __shfl_xor(s, 1);
      s += __shfl_xor(s, 2);
      s += __shfl_xor(s, 4);
      s += __shfl_xor(s, 8);
      if (c16 == 0) red[(rt * 16 + quad * 4 + r) * 4 + w] = s;
    }
  __syncthreads();
  float ss[4][4];
#pragma unroll
  for (int rt = 0; rt < 4; rt++)
#pragma unroll
    for (int r = 0; r < 4; r++) {
      int row = rt * 16 + quad * 4 + r;
      float tot = red[row * 4] + red[row * 4 + 1] + red[row * 4 + 2] + red[row * 4 + 3];
      ss[rt][r] = rsqrtf(tot * (1.0f / DVv) + EPSf);
    }
  __syncthreads();

#pragma unroll
  for (int n = 0; n < 8; n++) {
    int col = w * 128 + n * 16 + c16;
    float gw = gnw[col];
#pragma unroll
    for (int rt = 0; rt < 4; rt++)
#pragma unroll
      for (int r = 0; r < 4; r++) {
        int row = rt * 16 + quad * 4 + r;
        o_lds[row * 512 + col] = __float2bfloat16(acc[rt][n][r] * ss[rt][r] * gw);
      }
  }
  __syncthreads();

#pragma unroll
  for (int it = 0; it < 16; it++) {
    int cid = it * 256 + tid;
    int row = cid >> 6;
    int cp = (cid & 63) * 8;
    const ushort_t* gp = (const ushort_t*)g + ((size_t)(b * Tn + q0 + row) * NH + h) * DVv + cp;
    us8 gv = *(const us8*)gp;
    us8 ov;
#pragma unroll
    for (int e = 0; e < 8; e++) {
      float gf = bf2f_raw(gv[e]);
      float gate = gf / (1.0f + expf(-gf));
      float of = __bfloat162float(o_lds[row * 512 + cp + e]);
      ov[e] = f2bf_raw(of * gate);
    }
    *(us8*)((ushort_t*)X + ((size_t)(b * Tn + q0 + row) * NH + h) * DVv + cp) = ov;
  }
}

extern "C" void kernel_launch(void* const* d_in, const int* in_sizes, int n_in,
                              void* d_out, int out_size, void* d_ws, size_t ws_size,
                              hipStream_t stream) {
  const float* hs  = (const float*)d_in[0];
  const float* Wq  = (const float*)d_in[1];
  const float* Wk  = (const float*)d_in[2];
  const float* Wv  = (const float*)d_in[3];
  const float* Wg  = (const float*)d_in[4];
  const float* Wo  = (const float*)d_in[5];
  const float* gnw = (const float*)d_in[6];
  float* out = (float*)d_out;
  char* ws = (char*)d_ws;

  bf16* hsb = (bf16*)(ws);                    // 16 MB
  bf16* WqT = (bf16*)(ws + 16777216);         //  8 MB  } contiguous [4096][2048] for fused qk
  bf16* WkT = (bf16*)(ws + 25165824);         //  8 MB  }
  bf16* WvT = (bf16*)(ws + 33554432);         // 16 MB  } contiguous [8192][2048] for fused vg
  bf16* WgT = (bf16*)(ws + 50331648);         // 16 MB  }
  char* vSb = ws;                              // alias hsb/WqT/WkT (dead after q/k/v/g GEMMs)
  bf16* WoT = (bf16*)(ws + 33554432);         // alias WvT (dead after vg GEMM)
  bf16* qb = (bf16*)(ws + 67108864);          // 16 MB
  bf16* kb = (bf16*)(ws + 83886080);          // 16 MB
  bf16* vb = (bf16*)(ws + 100663296);         // 32 MB
  bf16* gb = (bf16*)(ws + 134217728);         // 32 MB
  bf16* Xb = vb;                               // alias v (dead after vS build)

  static bool attr_done = false;
  if (!attr_done) {
    hipFuncSetAttribute((const void*)k_gemm8, hipFuncAttributeMaxDynamicSharedMemorySize, 131072);
    attr_done = true;
  }

  dim3 tb(32, 8);

  k_f32_to_bf16<<<8192, 256, 0, stream>>>((const float4*)hs, (ushort4*)hsb, 2097152);
  k_transpose_w<<<dim3(HID / 32, HID / 32), tb, 0, stream>>>(Wq, WqT, HID, HID);
  k_transpose_w<<<dim3(HID / 32, HID / 32), tb, 0, stream>>>(Wk, WkT, HID, HID);
  k_transpose_w<<<dim3(NH * DVv / 32, HID / 32), tb, 0, stream>>>(Wv, WvT, HID, NH * DVv);
  k_transpose_w<<<dim3(NH * DVv / 32, HID / 32), tb, 0, stream>>>(Wg, WgT, HID, NH * DVv);
  // fused q|k: C[4096][4096] = hsb @ [WqT|WkT]^T, split at n=2048 -> qb, kb
  k_gemm8<<<dim3(16, 16), 512, 131072, stream>>>(hsb, WqT, qb, kb, 2048, 4096, 4096, 2048);
  // fused v|g: C[4096][8192] = hsb @ [WvT|WgT]^T, split at n=4096 -> vb, gb
  k_gemm8<<<dim3(32, 16), 512, 131072, stream>>>(hsb, WvT, vb, gb, 4096, 4096, 8192, 2048);
  k_rope<<<16384, 256, 0, stream>>>(qb, 0.0625f);
  k_rope<<<16384, 256, 0, stream>>>(kb, 1.0f);
  k_build_vS<<<dim3(64, 16), 256, 0, stream>>>((const ushort_t*)vb, (ushort_t*)vSb);
  k_transpose_w<<<dim3(HID / 32, NH * DVv / 32), tb, 0, stream>>>(Wo, WoT, NH * DVv, HID);
  k_retention<<<512, 256, 0, stream>>>(qb, kb, vSb, gb, gnw, Xb);
  k_gemm<false><<<dim3(16, 32), 256, 0, stream>>>(Xb, WoT, out, 4096, 2048, 4096);
}

// Round 3
// 676.820 us; speedup vs baseline: 1.0271x; 1.0271x over previous
//
#include <hip/hip_runtime.h>
#include <hip/hip_bf16.h>
#include <math.h>

#define NH 8
#define DKk 256
#define DVv 512
#define Bn 2
#define Tn 2048
#define HID 2048
#define EPSf 1e-5f

typedef __bf16 bf16x8 __attribute__((ext_vector_type(8)));
typedef float f32x4 __attribute__((ext_vector_type(4)));
typedef unsigned short us8 __attribute__((ext_vector_type(8)));
using bf16 = __hip_bfloat16;
typedef unsigned short ushort_t;

__device__ __forceinline__ void gload_lds16(const void* g, void* lds_base) {
  __builtin_amdgcn_global_load_lds(
      (const __attribute__((address_space(1))) void*)g,
      (__attribute__((address_space(3))) void*)lds_base, 16, 0, 0);
}

__device__ __forceinline__ ushort_t f2bf_raw(float f) {
  bf16 h = __float2bfloat16(f);
  return *reinterpret_cast<ushort_t*>(&h);
}
__device__ __forceinline__ float bf2f_raw(ushort_t u) {
  union { unsigned int i; float f; } v; v.i = ((unsigned int)u) << 16; return v.f;
}

// ---------------- fp32 -> bf16 elementwise (vectorized x4) ----------------
__global__ void k_f32_to_bf16(const float4* __restrict__ in, ushort4* __restrict__ out, int n4) {
  int i = blockIdx.x * blockDim.x + threadIdx.x;
  if (i >= n4) return;
  float4 v = in[i];
  ushort4 o;
  o.x = f2bf_raw(v.x); o.y = f2bf_raw(v.y); o.z = f2bf_raw(v.z); o.w = f2bf_raw(v.w);
  out[i] = o;
}

// ---------------- W (K,N) fp32 -> WT (N,K) bf16 ----------------
__global__ void k_transpose_w(const float* __restrict__ W, bf16* __restrict__ WT, int K, int N) {
  __shared__ float t[32][33];
  int n0 = blockIdx.x * 32, k0 = blockIdx.y * 32;
  int tx = threadIdx.x, ty = threadIdx.y;
#pragma unroll
  for (int i = 0; i < 4; i++)
    t[ty + i * 8][tx] = W[(size_t)(k0 + ty + i * 8) * N + n0 + tx];
  __syncthreads();
#pragma unroll
  for (int i = 0; i < 4; i++)
    WT[(size_t)(n0 + ty + i * 8) * K + k0 + tx] = __float2bfloat16(t[tx][ty + i * 8]);
}

// ---------------- v (b,t,h,dv) bf16 -> vS[bh][kt][chunk(4)][dv(512)] 16B units ----------------
__global__ void k_build_vS(const ushort_t* __restrict__ v, ushort_t* __restrict__ vS) {
  __shared__ ushort_t t[32 * 520];
  const int tid = threadIdx.x;
  const int kt = blockIdx.x;
  const int bh = blockIdx.y;
  const int b = bh >> 3, h = bh & 7;
#pragma unroll
  for (int r = 0; r < 8; r++) {
    int j = r * 4 + (tid >> 6);
    int vec = tid & 63;
    us8 d = *(const us8*)(v + (((size_t)(b * Tn + kt * 32 + j) * NH + h) * DVv) + vec * 8);
    *(us8*)(&t[j * 520 + vec * 8]) = d;
  }
  __syncthreads();
#pragma unroll
  for (int u = 0; u < 8; u++) {
    int uid = u * 256 + tid;
    int chunk = uid >> 9;
    int dv = uid & 511;
    us8 o;
#pragma unroll
    for (int jj = 0; jj < 8; jj++) o[jj] = t[(chunk * 8 + jj) * 520 + dv];
    *(us8*)(vS + ((size_t)(bh * 64 + kt) * 2048 + chunk * 512 + dv) * 8) = o;
  }
}

// ---------------- RoPE in-place on bf16 (b,t,h,dk), scale folded ----------------
__global__ void k_rope(bf16* __restrict__ x, float scale) {
  int tid = blockIdx.x * 256 + threadIdx.x;
  int i = tid & 127;
  int h = (tid >> 7) & 7;
  int t = (tid >> 10) & (Tn - 1);
  int b = tid >> 21;
  float inv = exp2f(-(float)i * (13.287712379549449f / 128.0f));
  float ang = (float)t * inv;
  float s, c;
  sincosf(ang, &s, &c);
  size_t base = ((size_t)(b * Tn + t) * NH + h) * DKk + i;
  float x1 = __bfloat162float(x[base]);
  float x2 = __bfloat162float(x[base + 128]);
  x[base]       = __float2bfloat16((x1 * c - x2 * s) * scale);
  x[base + 128] = __float2bfloat16((x2 * c + x1 * s) * scale);
}

// ---------------- m97-style GEMM (out-proj) + XCD y-major chunk swizzle ----------------
template <bool OUT_BF16>
__global__ __launch_bounds__(256) void k_gemm(const bf16* __restrict__ A, const bf16* __restrict__ BT,
                                              void* __restrict__ Cout, int M, int N, int K) {
  __shared__ __align__(16) bf16 a_lds[128 * 32];
  __shared__ __align__(16) bf16 b_lds[128 * 32];
  const int tid = threadIdx.x;
  const int l = tid & 63;
  const int w = tid >> 6;
  const int wr = w >> 1, wc = w & 1;
  const int bid = blockIdx.y * gridDim.x + blockIdx.x;
  const int cpx = (gridDim.x * gridDim.y) >> 3;
  const int s = (bid & 7) * cpx + (bid >> 3);
  const int bx = s / gridDim.y, by = s % gridDim.y;
  const int m0 = by * 128, n0 = bx * 128;
  const int quad = l >> 4, c16 = l & 15;

  const int lrow = l >> 2;
  const int loff = (l & 3) * 16;
  const char* aG0 = (const char*)(A + (size_t)(m0 + w * 32 + lrow) * K) + loff;
  const char* aG1 = (const char*)(A + (size_t)(m0 + w * 32 + 16 + lrow) * K) + loff;
  const char* bG0 = (const char*)(BT + (size_t)(n0 + w * 32 + lrow) * K) + loff;
  const char* bG1 = (const char*)(BT + (size_t)(n0 + w * 32 + 16 + lrow) * K) + loff;
  char* aL0 = (char*)a_lds + w * 2048;
  char* aL1 = (char*)a_lds + w * 2048 + 1024;
  char* bL0 = (char*)b_lds + w * 2048;
  char* bL1 = (char*)b_lds + w * 2048 + 1024;

  f32x4 acc[4][4];
  const f32x4 fz = {0.f, 0.f, 0.f, 0.f};
#pragma unroll
  for (int r = 0; r < 4; r++)
#pragma unroll
    for (int c = 0; c < 4; c++) acc[r][c] = fz;

  for (int k0 = 0; k0 < K; k0 += 32) {
    __syncthreads();
    size_t kb = (size_t)k0 * 2;
    gload_lds16(aG0 + kb, aL0);
    gload_lds16(aG1 + kb, aL1);
    gload_lds16(bG0 + kb, bL0);
    gload_lds16(bG1 + kb, bL1);
    __syncthreads();
    bf16x8 af[4], bfv[4];
#pragma unroll
    for (int r = 0; r < 4; r++)
      af[r] = *(const bf16x8*)(a_lds + (wr * 64 + r * 16 + c16) * 32 + quad * 8);
#pragma unroll
    for (int c = 0; c < 4; c++)
      bfv[c] = *(const bf16x8*)(b_lds + (wc * 64 + c * 16 + c16) * 32 + quad * 8);
#pragma unroll
    for (int r = 0; r < 4; r++)
#pragma unroll
      for (int c = 0; c < 4; c++)
        acc[r][c] = __builtin_amdgcn_mfma_f32_16x16x32_bf16(af[r], bfv[c], acc[r][c], 0, 0, 0);
  }

#pragma unroll
  for (int r = 0; r < 4; r++)
#pragma unroll
    for (int c = 0; c < 4; c++)
#pragma unroll
      for (int rr = 0; rr < 4; rr++) {
        int m = m0 + wr * 64 + r * 16 + quad * 4 + rr;
        int n = n0 + wc * 64 + c * 16 + c16;
        float val = acc[r][c][rr];
        if (OUT_BF16) ((bf16*)Cout)[(size_t)m * N + n] = __float2bfloat16(val);
        else          ((float*)Cout)[(size_t)m * N + n] = val;
      }
}

// ================= 256x256 8-phase GEMM, v2 schedule (4-phase slack) =================
#define BARX() asm volatile("s_barrier" ::: "memory")
#define LGKM0() { asm volatile("s_waitcnt lgkmcnt(0)" ::: "memory"); __builtin_amdgcn_sched_barrier(0); }
#define VMW8() asm volatile("s_waitcnt vmcnt(8)" ::: "memory")
#define VMW0() asm volatile("s_waitcnt vmcnt(0)" ::: "memory")
#define PRIO1 __builtin_amdgcn_s_setprio(1)
#define PRIO0 __builtin_amdgcn_s_setprio(0)

#define QUADX(MH, NHh)                                                             \
  { _Pragma("unroll") for (int kk_ = 0; kk_ < 2; ++kk_)                            \
    _Pragma("unroll") for (int mf_ = 0; mf_ < 4; ++mf_)                            \
    _Pragma("unroll") for (int nf_ = 0; nf_ < 2; ++nf_)                            \
      acc[(MH)*4 + mf_][(NHh)*2 + nf_] = __builtin_amdgcn_mfma_f32_16x16x32_bf16(  \
          ar[(MH)*4 + mf_][kk_], br[(NHh)*2 + nf_][kk_],                           \
          acc[(MH)*4 + mf_][(NHh)*2 + nf_], 0, 0, 0); }

__global__ __launch_bounds__(512, 2) void k_gemm8(const bf16* __restrict__ A, const bf16* __restrict__ BT,
                                                  bf16* __restrict__ O0, bf16* __restrict__ O1,
                                                  int nsplit, int M, int Ntot, int K) {
  extern __shared__ char lds[];
  const int tid = threadIdx.x;
  const int lane = tid & 63;
  const int w = tid >> 6;        // 0..7
  const int wr = w >> 2;         // 0..1 (M half)
  const int wc = w & 3;          // 0..3 (N quarter)
  const int quad = lane >> 4, c16 = lane & 15;
  const int bid = blockIdx.y * gridDim.x + blockIdx.x;
  const int cpx = (gridDim.x * gridDim.y) >> 3;
  const int sw = (bid & 7) * cpx + (bid >> 3);
  const int bx = sw / gridDim.y, by = sw % gridDim.y;
  const int m0 = by * 256, n0 = bx * 256;

  const int srow = (w << 4) | (lane >> 3);
  const int gsw = (((lane & 7) ^ (lane >> 3)) << 4);
  const size_t rowBytes = (size_t)K * 2;
  const char* aS = (const char*)(A + (size_t)(m0 + srow) * K) + gsw;
  const char* bS = (const char*)(BT + (size_t)(n0 + srow) * K) + gsw;

  auto stage = [&](int matB, int buf, int h, int t) {
    const char* base = (matB ? bS : aS) + (size_t)h * 128 * rowBytes + (size_t)t * 128;
    char* ldst = lds + buf * 65536 + matB * 32768 + h * 16384 + w * 2048;
    gload_lds16(base, ldst);
    gload_lds16(base + 8 * rowBytes, ldst + 1024);
  };
  auto ldA = [&](int buf, int mf, int kk) -> bf16x8 {
    int row = wr * 128 + mf * 16 + c16;
    return *(const bf16x8*)(lds + buf * 65536 + row * 128 + ((((kk << 2) | quad) ^ (c16 & 7)) << 4));
  };
  auto ldB = [&](int buf, int nf, int kk) -> bf16x8 {
    int row = wc * 64 + nf * 16 + c16;
    return *(const bf16x8*)(lds + buf * 65536 + 32768 + row * 128 + ((((kk << 2) | quad) ^ (c16 & 7)) << 4));
  };

  f32x4 acc[8][4];
  const f32x4 fz = {0.f, 0.f, 0.f, 0.f};
#pragma unroll
  for (int i = 0; i < 8; i++)
#pragma unroll
    for (int j = 0; j < 4; j++) acc[i][j] = fz;
  bf16x8 ar[8][2], br[4][2];

  const int nT = K >> 6;
  const int nIter = nT >> 1;

  stage(0, 0, 0, 0); stage(0, 0, 1, 0);
  stage(1, 0, 0, 0); stage(1, 0, 1, 0);
  stage(0, 1, 0, 1); stage(0, 1, 1, 1);
  stage(1, 1, 0, 1); stage(1, 1, 1, 1);
  VMW8();
  BARX();

  for (int it = 0; it < nIter; ++it) {
    const int t = it * 2;
    const bool last = (it == nIter - 1);
#pragma unroll
    for (int mf = 0; mf < 4; ++mf) { ar[mf][0] = ldA(0, mf, 0); ar[mf][1] = ldA(0, mf, 1); }
#pragma unroll
    for (int nf = 0; nf < 2; ++nf) { br[nf][0] = ldB(0, nf, 0); br[nf][1] = ldB(0, nf, 1); }
    BARX(); LGKM0();
    PRIO1; QUADX(0, 0); PRIO0;
    BARX();
#pragma unroll
    for (int mf = 4; mf < 8; ++mf) { ar[mf][0] = ldA(0, mf, 0); ar[mf][1] = ldA(0, mf, 1); }
#pragma unroll
    for (int nf = 2; nf < 4; ++nf) { br[nf][0] = ldB(0, nf, 0); br[nf][1] = ldB(0, nf, 1); }
    BARX(); LGKM0();
    PRIO1; QUADX(0, 1); PRIO0;
    BARX();
    if (!last) { stage(0, 0, 0, t + 2); stage(0, 0, 1, t + 2); }
    BARX();
    PRIO1; QUADX(1, 0); PRIO0;
    BARX();
    if (!last) { stage(1, 0, 0, t + 2); stage(1, 0, 1, t + 2); }
    BARX();
    PRIO1; QUADX(1, 1); PRIO0;
    if (!last) { VMW8(); } else { VMW0(); }
    BARX();
#pragma unroll
    for (int mf = 0; mf < 4; ++mf) { ar[mf][0] = ldA(1, mf, 0); ar[mf][1] = ldA(1, mf, 1); }
#pragma unroll
    for (int nf = 0; nf < 2; ++nf) { br[nf][0] = ldB(1, nf, 0); br[nf][1] = ldB(1, nf, 1); }
    BARX(); LGKM0();
    PRIO1; QUADX(0, 0); PRIO0;
    BARX();
#pragma unroll
    for (int mf = 4; mf < 8; ++mf) { ar[mf][0] = ldA(1, mf, 0); ar[mf][1] = ldA(1, mf, 1); }
#pragma unroll
    for (int nf = 2; nf < 4; ++nf) { br[nf][0] = ldB(1, nf, 0); br[nf][1] = ldB(1, nf, 1); }
    BARX(); LGKM0();
    PRIO1; QUADX(0, 1); PRIO0;
    BARX();
    if (!last) { stage(0, 1, 0, t + 3); stage(0, 1, 1, t + 3); }
    BARX();
    PRIO1; QUADX(1, 0); PRIO0;
    BARX();
    if (!last) { stage(1, 1, 0, t + 3); stage(1, 1, 1, t + 3); }
    BARX();
    PRIO1; QUADX(1, 1); PRIO0;
    if (!last) VMW8();
    BARX();
  }

  bf16* Ob; int ldo, nc0;
  if (n0 < nsplit) { Ob = O0; ldo = nsplit; nc0 = n0; }
  else             { Ob = O1; ldo = Ntot - nsplit; nc0 = n0 - nsplit; }
#pragma unroll
  for (int mf = 0; mf < 8; ++mf)
#pragma unroll
    for (int nf = 0; nf < 4; ++nf)
#pragma unroll
      for (int rr = 0; rr < 4; ++rr) {
        int m = m0 + wr * 128 + mf * 16 + quad * 4 + rr;
        int n = nc0 + wc * 64 + nf * 16 + c16;
        Ob[(size_t)m * ldo + n] = __float2bfloat16(acc[mf][nf][rr]);
      }
}

// ---------------- Retention v3: K+V full double-buffer, counted vmcnt, heavy-first ----------------
// LDS (dynamic 104448B): K[2][16KB]@0, V[2][32KB]@32768, p@98304 (5120B), red@103424 (1KB).
// 1 block/CU; 512 blocks oversubscribe 2:1 -> heavy-first (qt desc) gives backfill balance.
// Per-wave ledger: 12 loads/tile (4 K + 8 V). Iter top: stage(t+1) -> 24 out; vmcnt(12)
// drains exactly tile t; barrier -> all waves see t in LDS. Tile t+1 flies across the whole
// iteration's S+P+PV (~600cy). Trailing lgkmcnt(0)+barrier = write-after-read safety for the
// buffer staged next iter. Mid lgkm-barrier = p_lds visibility (vmcnt untouched).
__global__ __launch_bounds__(256, 1) void k_retention(const bf16* __restrict__ q, const bf16* __restrict__ k,
                                                      const char* __restrict__ vS, const bf16* __restrict__ g,
                                                      const float* __restrict__ gnw, bf16* __restrict__ X) {
  extern __shared__ char smem[];
  ushort_t* p_lds = (ushort_t*)(smem + 98304);  // [64 rows] stride 40 ushorts (80B)
  float* red = (float*)(smem + 103424);         // [64][4]
  bf16* o_lds = (bf16*)smem;                    // epilogue alias (64KB)

  const int tid = threadIdx.x;
  const int l = tid & 63, w = tid >> 6;
  const int quad = l >> 4, c16 = l & 15;

  const int bid = blockIdx.x;
  const int qt = 31 - (bid >> 4);   // heavy-first: largest kt ranges launch first
  const int bh = bid & 15;
  const int b = bh >> 3, h = bh & 7;
  const int q0 = qt * 64;

  bf16x8 qf[8];
  {
    const bf16* qrow = q + ((size_t)(b * Tn + q0 + w * 16 + c16) * NH + h) * DKk + quad * 8;
#pragma unroll
    for (int c = 0; c < 8; c++) qf[c] = *(const bf16x8*)(qrow + c * 32);
  }

  const float log2g = log2f(1.0f - exp2f(-5.0f - (float)h));

  f32x4 acc[4][8];
  const f32x4 fz = {0.f, 0.f, 0.f, 0.f};
#pragma unroll
  for (int rt = 0; rt < 4; rt++)
#pragma unroll
    for (int n = 0; n < 8; n++) acc[rt][n] = fz;

  const int ktmax = 2 * qt + 1;
  const float Dcut = 30.0f / (-log2g);
  int kt0 = (int)fmaxf(0.0f, floorf(((float)q0 - Dcut) * (1.0f / 32.0f)));

  const char* vS_tilebase = vS + (size_t)(bh * 64) * 32768;

  auto stageKV = [&](int kt, int pbuf) {
    // K: 16 instrs (4/wave); instr = 2 j-rows x 512B, 16B-granule XOR swizzle via source
#pragma unroll
    for (int i = 0; i < 4; i++) {
      int instr = w * 4 + i;
      int j = instr * 2 + (l >> 5);
      int cg = (l & 31) ^ (j & 7);
      const char* gp = (const char*)(k + ((size_t)(b * Tn + kt * 32 + j) * NH + h) * DKk) + cg * 16;
      gload_lds16(gp, smem + pbuf * 16384 + instr * 1024);
    }
    // V: 32 instrs (8/wave), fully contiguous 1KB each
#pragma unroll
    for (int i = 0; i < 8; i++) {
      int instr = w * 8 + i;
      const char* gp = vS_tilebase + (size_t)kt * 32768 + instr * 1024 + l * 16;
      gload_lds16(gp, smem + 32768 + pbuf * 32768 + instr * 1024);
    }
  };

  stageKV(kt0, 0);   // 12 loads/wave outstanding

  for (int kt = kt0; kt <= ktmax; kt++) {
    const int pb = (kt - kt0) & 1;
    if (kt < ktmax) {
      stageKV(kt + 1, pb ^ 1);                          // 24 outstanding
      asm volatile("s_waitcnt vmcnt(12)" ::: "memory"); // drain exactly tile kt
    } else {
      asm volatile("s_waitcnt vmcnt(0)" ::: "memory");
    }
    __builtin_amdgcn_sched_barrier(0);
    __builtin_amdgcn_s_barrier();   // all waves: tile kt resident in LDS

    // S: wave's 16 rows x 32 j (2 j-tiles), K from buf pb
    f32x4 sacc[2] = {fz, fz};
#pragma unroll
    for (int jt = 0; jt < 2; jt++)
#pragma unroll
      for (int c = 0; c < 8; c++) {
        const char* kp = smem + pb * 16384 + (jt * 16 + c16) * 512 + (((c * 4 + quad) ^ (c16 & 7)) * 16);
        bf16x8 bfrag = *(const bf16x8*)kp;
        sacc[jt] = __builtin_amdgcn_mfma_f32_16x16x32_bf16(qf[c], bfrag, sacc[jt], 0, 0, 0);
      }

    // decay + causal mask -> P (bf16) in padded LDS
#pragma unroll
    for (int jt = 0; jt < 2; jt++)
#pragma unroll
      for (int r = 0; r < 4; r++) {
        int ig = q0 + w * 16 + quad * 4 + r;
        int jg = kt * 32 + jt * 16 + c16;
        int d = ig - jg;
        float val = (d >= 0) ? sacc[jt][r] * exp2f(log2g * (float)d) : 0.0f;
        p_lds[(w * 16 + quad * 4 + r) * 40 + jt * 16 + c16] = f2bf_raw(val);
      }
    // lgkm-only barrier: p visible; kt+1 gload_lds stays in flight
    asm volatile("s_waitcnt lgkmcnt(0)" ::: "memory");
    __builtin_amdgcn_sched_barrier(0);
    __builtin_amdgcn_s_barrier();

    // O += P @ V from buf pb: wave w covers dv = w*128..+127 for all 4 row-tiles
    bf16x8 pa[4];
#pragma unroll
    for (int rt = 0; rt < 4; rt++)
      pa[rt] = *(const bf16x8*)((const char*)p_lds + (rt * 16 + c16) * 80 + quad * 16);
    const char* v_lds = smem + 32768 + pb * 32768;
#pragma unroll
    for (int n = 0; n < 8; n++) {
      bf16x8 bv = *(const bf16x8*)(v_lds + quad * 8192 + (w * 128 + n * 16 + c16) * 16);
#pragma unroll
      for (int rt = 0; rt < 4; rt++)
        acc[rt][n] = __builtin_amdgcn_mfma_f32_16x16x32_bf16(pa[rt], bv, acc[rt][n], 0, 0, 0);
    }
    // trailing: all reads of buf pb done before next iter stages over pb (tile kt+2)
    asm volatile("s_waitcnt lgkmcnt(0)" ::: "memory");
    __builtin_amdgcn_sched_barrier(0);
    __builtin_amdgcn_s_barrier();
  }

  // RMS: wave has 128-dv partial for all 64 rows -> cross-wave combine via red
  __syncthreads();
#pragma unroll
  for (int rt = 0; rt < 4; rt++)
#pragma unroll
    for (int r = 0; r < 4; r++) {
      float s = 0.f;
#pragma unroll
      for (int n = 0; n < 8; n++) { float v = acc[rt][n][r]; s += v * v; }
      s += __shfl_xor(s, 1);
      s += __shfl_xor(s, 2);
      s += __shfl_xor(s, 4);
      s += __shfl_xor(s, 8);
      if (c16 == 0) red[(rt * 16 + quad * 4 + r) * 4 + w] = s;
    }
  __syncthreads();
  float ss[4][4];
#pragma unroll
  for (int rt = 0; rt < 4; rt++)
#pragma unroll
    for (int r = 0; r < 4; r++) {
      int row = rt * 16 + quad * 4 + r;
      float tot = red[row * 4] + red[row * 4 + 1] + red[row * 4 + 2] + red[row * 4 + 3];
      ss[rt][r] = rsqrtf(tot * (1.0f / DVv) + EPSf);
    }
  __syncthreads();

#pragma unroll
  for (int n = 0; n < 8; n++) {
    int col = w * 128 + n * 16 + c16;
    float gw = gnw[col];
#pragma unroll
    for (int rt = 0; rt < 4; rt++)
#pragma unroll
      for (int r = 0; r < 4; r++) {
        int row = rt * 16 + quad * 4 + r;
        o_lds[row * 512 + col] = __float2bfloat16(acc[rt][n][r] * ss[rt][r] * gw);
      }
  }
  __syncthreads();

#pragma unroll
  for (int it = 0; it < 16; it++) {
    int cid = it * 256 + tid;
    int row = cid >> 6;
    int cp = (cid & 63) * 8;
    const ushort_t* gp = (const ushort_t*)g + ((size_t)(b * Tn + q0 + row) * NH + h) * DVv + cp;
    us8 gv = *(const us8*)gp;
    us8 ov;
#pragma unroll
    for (int e = 0; e < 8; e++) {
      float gf = bf2f_raw(gv[e]);
      float gate = gf / (1.0f + expf(-gf));
      float of = __bfloat162float(o_lds[row * 512 + cp + e]);
      ov[e] = f2bf_raw(of * gate);
    }
    *(us8*)((ushort_t*)X + ((size_t)(b * Tn + q0 + row) * NH + h) * DVv + cp) = ov;
  }
}

extern "C" void kernel_launch(void* const* d_in, const int* in_sizes, int n_in,
                              void* d_out, int out_size, void* d_ws, size_t ws_size,
                              hipStream_t stream) {
  const float* hs  = (const float*)d_in[0];
  const float* Wq  = (const float*)d_in[1];
  const float* Wk  = (const float*)d_in[2];
  const float* Wv  = (const float*)d_in[3];
  const float* Wg  = (const float*)d_in[4];
  const float* Wo  = (const float*)d_in[5];
  const float* gnw = (const float*)d_in[6];
  float* out = (float*)d_out;
  char* ws = (char*)d_ws;

  bf16* hsb = (bf16*)(ws);                    // 16 MB
  bf16* WqT = (bf16*)(ws + 16777216);         //  8 MB  } contiguous [4096][2048] for fused qk
  bf16* WkT = (bf16*)(ws + 25165824);         //  8 MB  }
  bf16* WvT = (bf16*)(ws + 33554432);         // 16 MB  } contiguous [8192][2048] for fused vg
  bf16* WgT = (bf16*)(ws + 50331648);         // 16 MB  }
  char* vSb = ws;                              // alias hsb/WqT/WkT (dead after q/k/v/g GEMMs)
  bf16* WoT = (bf16*)(ws + 33554432);         // alias WvT (dead after vg GEMM)
  bf16* qb = (bf16*)(ws + 67108864);          // 16 MB
  bf16* kb = (bf16*)(ws + 83886080);          // 16 MB
  bf16* vb = (bf16*)(ws + 100663296);         // 32 MB
  bf16* gb = (bf16*)(ws + 134217728);         // 32 MB
  bf16* Xb = vb;                               // alias v (dead after vS build)

  static bool attr_done = false;
  if (!attr_done) {
    hipFuncSetAttribute((const void*)k_gemm8, hipFuncAttributeMaxDynamicSharedMemorySize, 131072);
    hipFuncSetAttribute((const void*)k_retention, hipFuncAttributeMaxDynamicSharedMemorySize, 104448);
    attr_done = true;
  }

  dim3 tb(32, 8);

  k_f32_to_bf16<<<8192, 256, 0, stream>>>((const float4*)hs, (ushort4*)hsb, 2097152);
  k_transpose_w<<<dim3(HID / 32, HID / 32), tb, 0, stream>>>(Wq, WqT, HID, HID);
  k_transpose_w<<<dim3(HID / 32, HID / 32), tb, 0, stream>>>(Wk, WkT, HID, HID);
  k_transpose_w<<<dim3(NH * DVv / 32, HID / 32), tb, 0, stream>>>(Wv, WvT, HID, NH * DVv);
  k_transpose_w<<<dim3(NH * DVv / 32, HID / 32), tb, 0, stream>>>(Wg, WgT, HID, NH * DVv);
  // fused q|k: C[4096][4096] = hsb @ [WqT|WkT]^T, split at n=2048 -> qb, kb
  k_gemm8<<<dim3(16, 16), 512, 131072, stream>>>(hsb, WqT, qb, kb, 2048, 4096, 4096, 2048);
  // fused v|g: C[4096][8192] = hsb @ [WvT|WgT]^T, split at n=4096 -> vb, gb
  k_gemm8<<<dim3(32, 16), 512, 131072, stream>>>(hsb, WvT, vb, gb, 4096, 4096, 8192, 2048);
  k_rope<<<16384, 256, 0, stream>>>(qb, 0.0625f);
  k_rope<<<16384, 256, 0, stream>>>(kb, 1.0f);
  k_build_vS<<<dim3(64, 16), 256, 0, stream>>>((const ushort_t*)vb, (ushort_t*)vSb);
  k_transpose_w<<<dim3(HID / 32, NH * DVv / 32), tb, 0, stream>>>(Wo, WoT, NH * DVv, HID);
  k_retention<<<512, 256, 104448, stream>>>(qb, kb, vSb, gb, gnw, Xb);
  k_gemm<false><<<dim3(16, 32), 256, 0, stream>>>(Xb, WoT, out, 4096, 2048, 4096);
}

// Round 4
// 645.494 us; speedup vs baseline: 1.0770x; 1.0485x over previous
//
#include <hip/hip_runtime.h>
#include <hip/hip_bf16.h>
#include <math.h>

#define NH 8
#define DKk 256
#define DVv 512
#define Bn 2
#define Tn 2048
#define HID 2048
#define EPSf 1e-5f

typedef __bf16 bf16x8 __attribute__((ext_vector_type(8)));
typedef float f32x4 __attribute__((ext_vector_type(4)));
typedef unsigned short us8 __attribute__((ext_vector_type(8)));
using bf16 = __hip_bfloat16;
typedef unsigned short ushort_t;

__device__ __forceinline__ void gload_lds16(const void* g, void* lds_base) {
  __builtin_amdgcn_global_load_lds(
      (const __attribute__((address_space(1))) void*)g,
      (__attribute__((address_space(3))) void*)lds_base, 16, 0, 0);
}

__device__ __forceinline__ ushort_t f2bf_raw(float f) {
  bf16 h = __float2bfloat16(f);
  return *reinterpret_cast<ushort_t*>(&h);
}
__device__ __forceinline__ float bf2f_raw(ushort_t u) {
  union { unsigned int i; float f; } v; v.i = ((unsigned int)u) << 16; return v.f;
}

// ---------------- fp32 -> bf16 elementwise (vectorized x4) ----------------
__global__ void k_f32_to_bf16(const float4* __restrict__ in, ushort4* __restrict__ out, int n4) {
  int i = blockIdx.x * blockDim.x + threadIdx.x;
  if (i >= n4) return;
  float4 v = in[i];
  ushort4 o;
  o.x = f2bf_raw(v.x); o.y = f2bf_raw(v.y); o.z = f2bf_raw(v.z); o.w = f2bf_raw(v.w);
  out[i] = o;
}

// ---------------- W (K,N) fp32 -> WT (N,K) bf16 ----------------
__global__ void k_transpose_w(const float* __restrict__ W, bf16* __restrict__ WT, int K, int N) {
  __shared__ float t[32][33];
  int n0 = blockIdx.x * 32, k0 = blockIdx.y * 32;
  int tx = threadIdx.x, ty = threadIdx.y;
#pragma unroll
  for (int i = 0; i < 4; i++)
    t[ty + i * 8][tx] = W[(size_t)(k0 + ty + i * 8) * N + n0 + tx];
  __syncthreads();
#pragma unroll
  for (int i = 0; i < 4; i++)
    WT[(size_t)(n0 + ty + i * 8) * K + k0 + tx] = __float2bfloat16(t[tx][ty + i * 8]);
}

// ---------------- v (b,t,h,dv) bf16 -> vS[bh][kt][chunk(4)][dv(512)] 16B units ----------------
__global__ void k_build_vS(const ushort_t* __restrict__ v, ushort_t* __restrict__ vS) {
  __shared__ ushort_t t[32 * 520];
  const int tid = threadIdx.x;
  const int kt = blockIdx.x;
  const int bh = blockIdx.y;
  const int b = bh >> 3, h = bh & 7;
#pragma unroll
  for (int r = 0; r < 8; r++) {
    int j = r * 4 + (tid >> 6);
    int vec = tid & 63;
    us8 d = *(const us8*)(v + (((size_t)(b * Tn + kt * 32 + j) * NH + h) * DVv) + vec * 8);
    *(us8*)(&t[j * 520 + vec * 8]) = d;
  }
  __syncthreads();
#pragma unroll
  for (int u = 0; u < 8; u++) {
    int uid = u * 256 + tid;
    int chunk = uid >> 9;
    int dv = uid & 511;
    us8 o;
#pragma unroll
    for (int jj = 0; jj < 8; jj++) o[jj] = t[(chunk * 8 + jj) * 520 + dv];
    *(us8*)(vS + ((size_t)(bh * 64 + kt) * 2048 + chunk * 512 + dv) * 8) = o;
  }
}

// ---------------- RoPE in-place on bf16 (b,t,h,dk), scale folded ----------------
__global__ void k_rope(bf16* __restrict__ x, float scale) {
  int tid = blockIdx.x * 256 + threadIdx.x;
  int i = tid & 127;
  int h = (tid >> 7) & 7;
  int t = (tid >> 10) & (Tn - 1);
  int b = tid >> 21;
  float inv = exp2f(-(float)i * (13.287712379549449f / 128.0f));
  float ang = (float)t * inv;
  float s, c;
  sincosf(ang, &s, &c);
  size_t base = ((size_t)(b * Tn + t) * NH + h) * DKk + i;
  float x1 = __bfloat162float(x[base]);
  float x2 = __bfloat162float(x[base + 128]);
  x[base]       = __float2bfloat16((x1 * c - x2 * s) * scale);
  x[base + 128] = __float2bfloat16((x2 * c + x1 * s) * scale);
}

// ---------------- m97-style GEMM (out-proj) ----------------
template <bool OUT_BF16>
__global__ __launch_bounds__(256) void k_gemm(const bf16* __restrict__ A, const bf16* __restrict__ BT,
                                              void* __restrict__ Cout, int M, int N, int K) {
  __shared__ __align__(16) bf16 a_lds[128 * 32];
  __shared__ __align__(16) bf16 b_lds[128 * 32];
  const int tid = threadIdx.x;
  const int l = tid & 63;
  const int w = tid >> 6;
  const int wr = w >> 1, wc = w & 1;
  const int m0 = blockIdx.y * 128, n0 = blockIdx.x * 128;
  const int quad = l >> 4, c16 = l & 15;

  const int lrow = l >> 2;
  const int loff = (l & 3) * 16;
  const char* aG0 = (const char*)(A + (size_t)(m0 + w * 32 + lrow) * K) + loff;
  const char* aG1 = (const char*)(A + (size_t)(m0 + w * 32 + 16 + lrow) * K) + loff;
  const char* bG0 = (const char*)(BT + (size_t)(n0 + w * 32 + lrow) * K) + loff;
  const char* bG1 = (const char*)(BT + (size_t)(n0 + w * 32 + 16 + lrow) * K) + loff;
  char* aL0 = (char*)a_lds + w * 2048;
  char* aL1 = (char*)a_lds + w * 2048 + 1024;
  char* bL0 = (char*)b_lds + w * 2048;
  char* bL1 = (char*)b_lds + w * 2048 + 1024;

  f32x4 acc[4][4];
  const f32x4 fz = {0.f, 0.f, 0.f, 0.f};
#pragma unroll
  for (int r = 0; r < 4; r++)
#pragma unroll
    for (int c = 0; c < 4; c++) acc[r][c] = fz;

  for (int k0 = 0; k0 < K; k0 += 32) {
    __syncthreads();
    size_t kb = (size_t)k0 * 2;
    gload_lds16(aG0 + kb, aL0);
    gload_lds16(aG1 + kb, aL1);
    gload_lds16(bG0 + kb, bL0);
    gload_lds16(bG1 + kb, bL1);
    __syncthreads();
    bf16x8 af[4], bfv[4];
#pragma unroll
    for (int r = 0; r < 4; r++)
      af[r] = *(const bf16x8*)(a_lds + (wr * 64 + r * 16 + c16) * 32 + quad * 8);
#pragma unroll
    for (int c = 0; c < 4; c++)
      bfv[c] = *(const bf16x8*)(b_lds + (wc * 64 + c * 16 + c16) * 32 + quad * 8);
#pragma unroll
    for (int r = 0; r < 4; r++)
#pragma unroll
      for (int c = 0; c < 4; c++)
        acc[r][c] = __builtin_amdgcn_mfma_f32_16x16x32_bf16(af[r], bfv[c], acc[r][c], 0, 0, 0);
  }

#pragma unroll
  for (int r = 0; r < 4; r++)
#pragma unroll
    for (int c = 0; c < 4; c++)
#pragma unroll
      for (int rr = 0; rr < 4; rr++) {
        int m = m0 + wr * 64 + r * 16 + quad * 4 + rr;
        int n = n0 + wc * 64 + c * 16 + c16;
        float val = acc[r][c][rr];
        if (OUT_BF16) ((bf16*)Cout)[(size_t)m * N + n] = __float2bfloat16(val);
        else          ((float*)Cout)[(size_t)m * N + n] = val;
      }
}

// ================= 256x256 8-phase GEMM, v2 schedule (4-phase slack), identity mapping =====
#define BARX() asm volatile("s_barrier" ::: "memory")
#define LGKM0() { asm volatile("s_waitcnt lgkmcnt(0)" ::: "memory"); __builtin_amdgcn_sched_barrier(0); }
#define VMW8() asm volatile("s_waitcnt vmcnt(8)" ::: "memory")
#define VMW0() asm volatile("s_waitcnt vmcnt(0)" ::: "memory")
#define PRIO1 __builtin_amdgcn_s_setprio(1)
#define PRIO0 __builtin_amdgcn_s_setprio(0)

#define QUADX(MH, NHh)                                                             \
  { _Pragma("unroll") for (int kk_ = 0; kk_ < 2; ++kk_)                            \
    _Pragma("unroll") for (int mf_ = 0; mf_ < 4; ++mf_)                            \
    _Pragma("unroll") for (int nf_ = 0; nf_ < 2; ++nf_)                            \
      acc[(MH)*4 + mf_][(NHh)*2 + nf_] = __builtin_amdgcn_mfma_f32_16x16x32_bf16(  \
          ar[(MH)*4 + mf_][kk_], br[(NHh)*2 + nf_][kk_],                           \
          acc[(MH)*4 + mf_][(NHh)*2 + nf_], 0, 0, 0); }

__global__ __launch_bounds__(512, 2) void k_gemm8(const bf16* __restrict__ A, const bf16* __restrict__ BT,
                                                  bf16* __restrict__ O0, bf16* __restrict__ O1,
                                                  int nsplit, int M, int Ntot, int K) {
  extern __shared__ char lds[];
  const int tid = threadIdx.x;
  const int lane = tid & 63;
  const int w = tid >> 6;        // 0..7
  const int wr = w >> 2;         // 0..1 (M half)
  const int wc = w & 3;          // 0..3 (N quarter)
  const int quad = lane >> 4, c16 = lane & 15;
  const int m0 = blockIdx.y * 256, n0 = blockIdx.x * 256;

  const int srow = (w << 4) | (lane >> 3);
  const int gsw = (((lane & 7) ^ (lane >> 3)) << 4);
  const size_t rowBytes = (size_t)K * 2;
  const char* aS = (const char*)(A + (size_t)(m0 + srow) * K) + gsw;
  const char* bS = (const char*)(BT + (size_t)(n0 + srow) * K) + gsw;

  auto stage = [&](int matB, int buf, int h, int t) {
    const char* base = (matB ? bS : aS) + (size_t)h * 128 * rowBytes + (size_t)t * 128;
    char* ldst = lds + buf * 65536 + matB * 32768 + h * 16384 + w * 2048;
    gload_lds16(base, ldst);
    gload_lds16(base + 8 * rowBytes, ldst + 1024);
  };
  auto ldA = [&](int buf, int mf, int kk) -> bf16x8 {
    int row = wr * 128 + mf * 16 + c16;
    return *(const bf16x8*)(lds + buf * 65536 + row * 128 + ((((kk << 2) | quad) ^ (c16 & 7)) << 4));
  };
  auto ldB = [&](int buf, int nf, int kk) -> bf16x8 {
    int row = wc * 64 + nf * 16 + c16;
    return *(const bf16x8*)(lds + buf * 65536 + 32768 + row * 128 + ((((kk << 2) | quad) ^ (c16 & 7)) << 4));
  };

  f32x4 acc[8][4];
  const f32x4 fz = {0.f, 0.f, 0.f, 0.f};
#pragma unroll
  for (int i = 0; i < 8; i++)
#pragma unroll
    for (int j = 0; j < 4; j++) acc[i][j] = fz;
  bf16x8 ar[8][2], br[4][2];

  const int nT = K >> 6;
  const int nIter = nT >> 1;

  stage(0, 0, 0, 0); stage(0, 0, 1, 0);
  stage(1, 0, 0, 0); stage(1, 0, 1, 0);
  stage(0, 1, 0, 1); stage(0, 1, 1, 1);
  stage(1, 1, 0, 1); stage(1, 1, 1, 1);
  VMW8();
  BARX();

  for (int it = 0; it < nIter; ++it) {
    const int t = it * 2;
    const bool last = (it == nIter - 1);
#pragma unroll
    for (int mf = 0; mf < 4; ++mf) { ar[mf][0] = ldA(0, mf, 0); ar[mf][1] = ldA(0, mf, 1); }
#pragma unroll
    for (int nf = 0; nf < 2; ++nf) { br[nf][0] = ldB(0, nf, 0); br[nf][1] = ldB(0, nf, 1); }
    BARX(); LGKM0();
    PRIO1; QUADX(0, 0); PRIO0;
    BARX();
#pragma unroll
    for (int mf = 4; mf < 8; ++mf) { ar[mf][0] = ldA(0, mf, 0); ar[mf][1] = ldA(0, mf, 1); }
#pragma unroll
    for (int nf = 2; nf < 4; ++nf) { br[nf][0] = ldB(0, nf, 0); br[nf][1] = ldB(0, nf, 1); }
    BARX(); LGKM0();
    PRIO1; QUADX(0, 1); PRIO0;
    BARX();
    if (!last) { stage(0, 0, 0, t + 2); stage(0, 0, 1, t + 2); }
    BARX();
    PRIO1; QUADX(1, 0); PRIO0;
    BARX();
    if (!last) { stage(1, 0, 0, t + 2); stage(1, 0, 1, t + 2); }
    BARX();
    PRIO1; QUADX(1, 1); PRIO0;
    if (!last) { VMW8(); } else { VMW0(); }
    BARX();
#pragma unroll
    for (int mf = 0; mf < 4; ++mf) { ar[mf][0] = ldA(1, mf, 0); ar[mf][1] = ldA(1, mf, 1); }
#pragma unroll
    for (int nf = 0; nf < 2; ++nf) { br[nf][0] = ldB(1, nf, 0); br[nf][1] = ldB(1, nf, 1); }
    BARX(); LGKM0();
    PRIO1; QUADX(0, 0); PRIO0;
    BARX();
#pragma unroll
    for (int mf = 4; mf < 8; ++mf) { ar[mf][0] = ldA(1, mf, 0); ar[mf][1] = ldA(1, mf, 1); }
#pragma unroll
    for (int nf = 2; nf < 4; ++nf) { br[nf][0] = ldB(1, nf, 0); br[nf][1] = ldB(1, nf, 1); }
    BARX(); LGKM0();
    PRIO1; QUADX(0, 1); PRIO0;
    BARX();
    if (!last) { stage(0, 1, 0, t + 3); stage(0, 1, 1, t + 3); }
    BARX();
    PRIO1; QUADX(1, 0); PRIO0;
    BARX();
    if (!last) { stage(1, 1, 0, t + 3); stage(1, 1, 1, t + 3); }
    BARX();
    PRIO1; QUADX(1, 1); PRIO0;
    if (!last) VMW8();
    BARX();
  }

  bf16* Ob; int ldo, nc0;
  if (n0 < nsplit) { Ob = O0; ldo = nsplit; nc0 = n0; }
  else             { Ob = O1; ldo = Ntot - nsplit; nc0 = n0 - nsplit; }
#pragma unroll
  for (int mf = 0; mf < 8; ++mf)
#pragma unroll
    for (int nf = 0; nf < 4; ++nf)
#pragma unroll
      for (int rr = 0; rr < 4; ++rr) {
        int m = m0 + wr * 128 + mf * 16 + quad * 4 + rr;
        int n = nc0 + wc * 64 + nf * 16 + c16;
        Ob[(size_t)m * ldo + n] = __float2bfloat16(acc[mf][nf][rr]);
      }
}

// ---------------- Retention v4: rotated loop {PV(t-1); S(t)}, K-dbuf + V-sbuf + P-dbuf ----
// LDS 76.8KB -> 2 blocks/CU (2 waves/SIMD, TLP) AND counted-vmcnt pipelining.
// Layout: K[2][16KB]@0; V[32KB]@32768; P[2][5120B]@65536; red[1KB]@75776.
// Per-wave ledger (qf loads are oldest, drained by first vmcnt(8)):
//   entry iter t: outstanding [V(t-1)(8), K(t)(4)]
//   vmcnt(4) -> V(t-1) landed; barrier; PV(t-1); lgkm0+barrier (V buf free)
//   issue V(t) (8); vmcnt(8) -> K(t) landed; barrier; S(t) -> P into p[par(t)]
//   issue K(t+1) (4); lgkm0+barrier (P visible, K[par(t+1)] reads long done)
// V(t) flies across S(t) (~half iter); K(t+1) flies across PV(t)+V-issue (~half iter).
// Block order: bid<256 heavy (qt=31-u), bid>=256 light (qt=u) -> CU pairs sum ~const.
__global__ __launch_bounds__(256, 2) void k_retention(const bf16* __restrict__ q, const bf16* __restrict__ k,
                                                      const char* __restrict__ vS, const bf16* __restrict__ g,
                                                      const float* __restrict__ gnw, bf16* __restrict__ X) {
  extern __shared__ char smem[];
  float* red = (float*)(smem + 75776);
  bf16* o_lds = (bf16*)smem;   // epilogue alias (64KB)

  const int tid = threadIdx.x;
  const int l = tid & 63, w = tid >> 6;
  const int quad = l >> 4, c16 = l & 15;

  const int bid = blockIdx.x;
  const int u = (bid & 255) >> 4;
  const int qt = (bid < 256) ? (31 - u) : u;   // heavy half then light half
  const int bh = bid & 15;
  const int b = bh >> 3, h = bh & 7;
  const int q0 = qt * 64;

  bf16x8 qf[8];
  {
    const bf16* qrow = q + ((size_t)(b * Tn + q0 + w * 16 + c16) * NH + h) * DKk + quad * 8;
#pragma unroll
    for (int c = 0; c < 8; c++) qf[c] = *(const bf16x8*)(qrow + c * 32);
  }

  const float log2g = log2f(1.0f - exp2f(-5.0f - (float)h));

  f32x4 acc[4][8];
  const f32x4 fz = {0.f, 0.f, 0.f, 0.f};
#pragma unroll
  for (int rt = 0; rt < 4; rt++)
#pragma unroll
    for (int n = 0; n < 8; n++) acc[rt][n] = fz;

  const int ktmax = 2 * qt + 1;
  const float Dcut = 30.0f / (-log2g);
  int kt0 = (int)fmaxf(0.0f, floorf(((float)q0 - Dcut) * (1.0f / 32.0f)));

  const char* vS_tilebase = vS + (size_t)(bh * 64) * 32768;

  auto stageK = [&](int kt) {
    const int pb = (kt - kt0) & 1;
#pragma unroll
    for (int i = 0; i < 1; i++) {
      int instr = w * 4;
      (void)instr;
    }
#pragma unroll
    for (int i = 0; i < 4; i++) {
      int instr = w * 4 + i;
      int j = instr * 2 + (l >> 5);
      int cg = (l & 31) ^ (j & 7);
      const char* gp = (const char*)(k + ((size_t)(b * Tn + kt * 32 + j) * NH + h) * DKk) + cg * 16;
      gload_lds16(gp, smem + pb * 16384 + instr * 1024);
    }
  };
  auto stageV = [&](int kt) {
#pragma unroll
    for (int i = 0; i < 8; i++) {
      int instr = w * 8 + i;
      const char* gp = vS_tilebase + (size_t)kt * 32768 + instr * 1024 + l * 16;
      gload_lds16(gp, smem + 32768 + instr * 1024);
    }
  };

  auto S_phase = [&](int kt) {
    const int pb = (kt - kt0) & 1;
    f32x4 sacc[2] = {fz, fz};
#pragma unroll
    for (int jt = 0; jt < 2; jt++)
#pragma unroll
      for (int c = 0; c < 8; c++) {
        const char* kp = smem + pb * 16384 + (jt * 16 + c16) * 512 + (((c * 4 + quad) ^ (c16 & 7)) * 16);
        bf16x8 bfrag = *(const bf16x8*)kp;
        sacc[jt] = __builtin_amdgcn_mfma_f32_16x16x32_bf16(qf[c], bfrag, sacc[jt], 0, 0, 0);
      }
    ushort_t* pbuf = (ushort_t*)(smem + 65536 + pb * 5120);
#pragma unroll
    for (int jt = 0; jt < 2; jt++)
#pragma unroll
      for (int r = 0; r < 4; r++) {
        int ig = q0 + w * 16 + quad * 4 + r;
        int jg = kt * 32 + jt * 16 + c16;
        int d = ig - jg;
        float val = (d >= 0) ? sacc[jt][r] * exp2f(log2g * (float)d) : 0.0f;
        pbuf[(w * 16 + quad * 4 + r) * 40 + jt * 16 + c16] = f2bf_raw(val);
      }
  };

  auto PV_phase = [&](int kt) {
    const int pb = (kt - kt0) & 1;
    const char* pbuf = smem + 65536 + pb * 5120;
    bf16x8 pa[4];
#pragma unroll
    for (int rt = 0; rt < 4; rt++)
      pa[rt] = *(const bf16x8*)(pbuf + (rt * 16 + c16) * 80 + quad * 16);
    const char* v_lds = smem + 32768;
#pragma unroll
    for (int n = 0; n < 8; n++) {
      bf16x8 bv = *(const bf16x8*)(v_lds + quad * 8192 + (w * 128 + n * 16 + c16) * 16);
#pragma unroll
      for (int rt = 0; rt < 4; rt++)
        acc[rt][n] = __builtin_amdgcn_mfma_f32_16x16x32_bf16(pa[rt], bv, acc[rt][n], 0, 0, 0);
    }
  };

#define SBAR() { __builtin_amdgcn_sched_barrier(0); __builtin_amdgcn_s_barrier(); }
#define WLGKM0() { asm volatile("s_waitcnt lgkmcnt(0)" ::: "memory"); }

  // ---- peeled first iteration (S-only) ----
  stageK(kt0);                                        // out: K(kt0)(4)  [+qf(8) older]
  stageV(kt0);                                        // out: +V(kt0)(8)
  asm volatile("s_waitcnt vmcnt(8)" ::: "memory");    // drains qf + K(kt0); V(kt0) flies
  SBAR();
  S_phase(kt0);
  if (kt0 + 1 <= ktmax) stageK(kt0 + 1);              // out: V(kt0)(8), K(kt0+1)(4)
  WLGKM0(); SBAR();

  // ---- main loop ----
  for (int kt = kt0 + 1; kt <= ktmax; ++kt) {
    asm volatile("s_waitcnt vmcnt(4)" ::: "memory");  // V(kt-1) landed; K(kt) flies
    SBAR();
    PV_phase(kt - 1);
    WLGKM0(); SBAR();                                 // V buf + p[kt-1] free
    stageV(kt);                                       // out: K(kt)(4), V(kt)(8)
    asm volatile("s_waitcnt vmcnt(8)" ::: "memory");  // K(kt) landed; V(kt) flies
    SBAR();
    S_phase(kt);
    if (kt + 1 <= ktmax) stageK(kt + 1);              // out: V(kt)(8), K(kt+1)(4)
    WLGKM0(); SBAR();                                 // p[kt] visible
  }

  // ---- epilogue PV(ktmax) ----
  asm volatile("s_waitcnt vmcnt(0)" ::: "memory");
  SBAR();
  PV_phase(ktmax);

  // RMS: wave has 128-dv partial for all 64 rows -> cross-wave combine via red
  __syncthreads();
#pragma unroll
  for (int rt = 0; rt < 4; rt++)
#pragma unroll
    for (int r = 0; r < 4; r++) {
      float s = 0.f;
#pragma unroll
      for (int n = 0; n < 8; n++) { float v = acc[rt][n][r]; s += v * v; }
      s += __shfl_xor(s, 1);
      s += __shfl_xor(s, 2);
      s += __shfl_xor(s, 4);
      s += __shfl_xor(s, 8);
      if (c16 == 0) red[(rt * 16 + quad * 4 + r) * 4 + w] = s;
    }
  __syncthreads();
  float ss[4][4];
#pragma unroll
  for (int rt = 0; rt < 4; rt++)
#pragma unroll
    for (int r = 0; r < 4; r++) {
      int row = rt * 16 + quad * 4 + r;
      float tot = red[row * 4] + red[row * 4 + 1] + red[row * 4 + 2] + red[row * 4 + 3];
      ss[rt][r] = rsqrtf(tot * (1.0f / DVv) + EPSf);
    }
  __syncthreads();

#pragma unroll
  for (int n = 0; n < 8; n++) {
    int col = w * 128 + n * 16 + c16;
    float gw = gnw[col];
#pragma unroll
    for (int rt = 0; rt < 4; rt++)
#pragma unroll
      for (int r = 0; r < 4; r++) {
        int row = rt * 16 + quad * 4 + r;
        o_lds[row * 512 + col] = __float2bfloat16(acc[rt][n][r] * ss[rt][r] * gw);
      }
  }
  __syncthreads();

#pragma unroll
  for (int it = 0; it < 16; it++) {
    int cid = it * 256 + tid;
    int row = cid >> 6;
    int cp = (cid & 63) * 8;
    const ushort_t* gp = (const ushort_t*)g + ((size_t)(b * Tn + q0 + row) * NH + h) * DVv + cp;
    us8 gv = *(const us8*)gp;
    us8 ov;
#pragma unroll
    for (int e = 0; e < 8; e++) {
      float gf = bf2f_raw(gv[e]);
      float gate = gf / (1.0f + expf(-gf));
      float of = __bfloat162float(o_lds[row * 512 + cp + e]);
      ov[e] = f2bf_raw(of * gate);
    }
    *(us8*)((ushort_t*)X + ((size_t)(b * Tn + q0 + row) * NH + h) * DVv + cp) = ov;
  }
}

extern "C" void kernel_launch(void* const* d_in, const int* in_sizes, int n_in,
                              void* d_out, int out_size, void* d_ws, size_t ws_size,
                              hipStream_t stream) {
  const float* hs  = (const float*)d_in[0];
  const float* Wq  = (const float*)d_in[1];
  const float* Wk  = (const float*)d_in[2];
  const float* Wv  = (const float*)d_in[3];
  const float* Wg  = (const float*)d_in[4];
  const float* Wo  = (const float*)d_in[5];
  const float* gnw = (const float*)d_in[6];
  float* out = (float*)d_out;
  char* ws = (char*)d_ws;

  bf16* hsb = (bf16*)(ws);                    // 16 MB
  bf16* WqT = (bf16*)(ws + 16777216);         //  8 MB  } contiguous [4096][2048] for fused qk
  bf16* WkT = (bf16*)(ws + 25165824);         //  8 MB  }
  bf16* WvT = (bf16*)(ws + 33554432);         // 16 MB  } contiguous [8192][2048] for fused vg
  bf16* WgT = (bf16*)(ws + 50331648);         // 16 MB  }
  char* vSb = ws;                              // alias hsb/WqT/WkT (dead after q/k/v/g GEMMs)
  bf16* WoT = (bf16*)(ws + 33554432);         // alias WvT (dead after vg GEMM)
  bf16* qb = (bf16*)(ws + 67108864);          // 16 MB
  bf16* kb = (bf16*)(ws + 83886080);          // 16 MB
  bf16* vb = (bf16*)(ws + 100663296);         // 32 MB
  bf16* gb = (bf16*)(ws + 134217728);         // 32 MB
  bf16* Xb = vb;                               // alias v (dead after vS build)

  static bool attr_done = false;
  if (!attr_done) {
    hipFuncSetAttribute((const void*)k_gemm8, hipFuncAttributeMaxDynamicSharedMemorySize, 131072);
    hipFuncSetAttribute((const void*)k_retention, hipFuncAttributeMaxDynamicSharedMemorySize, 76800);
    attr_done = true;
  }

  dim3 tb(32, 8);

  k_f32_to_bf16<<<8192, 256, 0, stream>>>((const float4*)hs, (ushort4*)hsb, 2097152);
  k_transpose_w<<<dim3(HID / 32, HID / 32), tb, 0, stream>>>(Wq, WqT, HID, HID);
  k_transpose_w<<<dim3(HID / 32, HID / 32), tb, 0, stream>>>(Wk, WkT, HID, HID);
  k_transpose_w<<<dim3(NH * DVv / 32, HID / 32), tb, 0, stream>>>(Wv, WvT, HID, NH * DVv);
  k_transpose_w<<<dim3(NH * DVv / 32, HID / 32), tb, 0, stream>>>(Wg, WgT, HID, NH * DVv);
  // fused q|k: C[4096][4096] = hsb @ [WqT|WkT]^T, split at n=2048 -> qb, kb
  k_gemm8<<<dim3(16, 16), 512, 131072, stream>>>(hsb, WqT, qb, kb, 2048, 4096, 4096, 2048);
  // fused v|g: C[4096][8192] = hsb @ [WvT|WgT]^T, split at n=4096 -> vb, gb
  k_gemm8<<<dim3(32, 16), 512, 131072, stream>>>(hsb, WvT, vb, gb, 4096, 4096, 8192, 2048);
  k_rope<<<16384, 256, 0, stream>>>(qb, 0.0625f);
  k_rope<<<16384, 256, 0, stream>>>(kb, 1.0f);
  k_build_vS<<<dim3(64, 16), 256, 0, stream>>>((const ushort_t*)vb, (ushort_t*)vSb);
  k_transpose_w<<<dim3(HID / 32, NH * DVv / 32), tb, 0, stream>>>(Wo, WoT, NH * DVv, HID);
  k_retention<<<512, 256, 76800, stream>>>(qb, kb, vSb, gb, gnw, Xb);
  k_gemm<false><<<dim3(16, 32), 256, 0, stream>>>(Xb, WoT, out, 4096, 2048, 4096);
}

// Round 5
// 621.096 us; speedup vs baseline: 1.1193x; 1.0393x over previous
//
#include <hip/hip_runtime.h>
#include <hip/hip_bf16.h>
#include <math.h>

#define NH 8
#define DKk 256
#define DVv 512
#define Bn 2
#define Tn 2048
#define HID 2048
#define EPSf 1e-5f

typedef __bf16 bf16x8 __attribute__((ext_vector_type(8)));
typedef float f32x4 __attribute__((ext_vector_type(4)));
typedef unsigned short us8 __attribute__((ext_vector_type(8)));
using bf16 = __hip_bfloat16;
typedef unsigned short ushort_t;

__device__ __forceinline__ void gload_lds16(const void* g, void* lds_base) {
  __builtin_amdgcn_global_load_lds(
      (const __attribute__((address_space(1))) void*)g,
      (__attribute__((address_space(3))) void*)lds_base, 16, 0, 0);
}

__device__ __forceinline__ ushort_t f2bf_raw(float f) {
  bf16 h = __float2bfloat16(f);
  return *reinterpret_cast<ushort_t*>(&h);
}
__device__ __forceinline__ float bf2f_raw(ushort_t u) {
  union { unsigned int i; float f; } v; v.i = ((unsigned int)u) << 16; return v.f;
}

// ---------------- fp32 -> bf16 elementwise (vectorized x4) ----------------
__global__ void k_f32_to_bf16(const float4* __restrict__ in, ushort4* __restrict__ out, int n4) {
  int i = blockIdx.x * blockDim.x + threadIdx.x;
  if (i >= n4) return;
  float4 v = in[i];
  ushort4 o;
  o.x = f2bf_raw(v.x); o.y = f2bf_raw(v.y); o.z = f2bf_raw(v.z); o.w = f2bf_raw(v.w);
  out[i] = o;
}

// ---------------- W (K,N) fp32 -> WT (N,K) bf16 ----------------
__global__ void k_transpose_w(const float* __restrict__ W, bf16* __restrict__ WT, int K, int N) {
  __shared__ float t[32][33];
  int n0 = blockIdx.x * 32, k0 = blockIdx.y * 32;
  int tx = threadIdx.x, ty = threadIdx.y;
#pragma unroll
  for (int i = 0; i < 4; i++)
    t[ty + i * 8][tx] = W[(size_t)(k0 + ty + i * 8) * N + n0 + tx];
  __syncthreads();
#pragma unroll
  for (int i = 0; i < 4; i++)
    WT[(size_t)(n0 + ty + i * 8) * K + k0 + tx] = __float2bfloat16(t[tx][ty + i * 8]);
}

// ---------------- v (b,t,h,dv) bf16 -> vS[bh][kt][chunk(4)][dv(512)] 16B units ----------------
__global__ void k_build_vS(const ushort_t* __restrict__ v, ushort_t* __restrict__ vS) {
  __shared__ ushort_t t[32 * 520];
  const int tid = threadIdx.x;
  const int kt = blockIdx.x;
  const int bh = blockIdx.y;
  const int b = bh >> 3, h = bh & 7;
#pragma unroll
  for (int r = 0; r < 8; r++) {
    int j = r * 4 + (tid >> 6);
    int vec = tid & 63;
    us8 d = *(const us8*)(v + (((size_t)(b * Tn + kt * 32 + j) * NH + h) * DVv) + vec * 8);
    *(us8*)(&t[j * 520 + vec * 8]) = d;
  }
  __syncthreads();
#pragma unroll
  for (int u = 0; u < 8; u++) {
    int uid = u * 256 + tid;
    int chunk = uid >> 9;
    int dv = uid & 511;
    us8 o;
#pragma unroll
    for (int jj = 0; jj < 8; jj++) o[jj] = t[(chunk * 8 + jj) * 520 + dv];
    *(us8*)(vS + ((size_t)(bh * 64 + kt) * 2048 + chunk * 512 + dv) * 8) = o;
  }
}

// ---------------- RoPE in-place on bf16 (b,t,h,dk), scale folded ----------------
__global__ void k_rope(bf16* __restrict__ x, float scale) {
  int tid = blockIdx.x * 256 + threadIdx.x;
  int i = tid & 127;
  int h = (tid >> 7) & 7;
  int t = (tid >> 10) & (Tn - 1);
  int b = tid >> 21;
  float inv = exp2f(-(float)i * (13.287712379549449f / 128.0f));
  float ang = (float)t * inv;
  float s, c;
  sincosf(ang, &s, &c);
  size_t base = ((size_t)(b * Tn + t) * NH + h) * DKk + i;
  float x1 = __bfloat162float(x[base]);
  float x2 = __bfloat162float(x[base + 128]);
  x[base]       = __float2bfloat16((x1 * c - x2 * s) * scale);
  x[base + 128] = __float2bfloat16((x2 * c + x1 * s) * scale);
}

// ---------------- m97-style GEMM (out-proj) ----------------
template <bool OUT_BF16>
__global__ __launch_bounds__(256) void k_gemm(const bf16* __restrict__ A, const bf16* __restrict__ BT,
                                              void* __restrict__ Cout, int M, int N, int K) {
  __shared__ __align__(16) bf16 a_lds[128 * 32];
  __shared__ __align__(16) bf16 b_lds[128 * 32];
  const int tid = threadIdx.x;
  const int l = tid & 63;
  const int w = tid >> 6;
  const int wr = w >> 1, wc = w & 1;
  const int m0 = blockIdx.y * 128, n0 = blockIdx.x * 128;
  const int quad = l >> 4, c16 = l & 15;

  const int lrow = l >> 2;
  const int loff = (l & 3) * 16;
  const char* aG0 = (const char*)(A + (size_t)(m0 + w * 32 + lrow) * K) + loff;
  const char* aG1 = (const char*)(A + (size_t)(m0 + w * 32 + 16 + lrow) * K) + loff;
  const char* bG0 = (const char*)(BT + (size_t)(n0 + w * 32 + lrow) * K) + loff;
  const char* bG1 = (const char*)(BT + (size_t)(n0 + w * 32 + 16 + lrow) * K) + loff;
  char* aL0 = (char*)a_lds + w * 2048;
  char* aL1 = (char*)a_lds + w * 2048 + 1024;
  char* bL0 = (char*)b_lds + w * 2048;
  char* bL1 = (char*)b_lds + w * 2048 + 1024;

  f32x4 acc[4][4];
  const f32x4 fz = {0.f, 0.f, 0.f, 0.f};
#pragma unroll
  for (int r = 0; r < 4; r++)
#pragma unroll
    for (int c = 0; c < 4; c++) acc[r][c] = fz;

  for (int k0 = 0; k0 < K; k0 += 32) {
    __syncthreads();
    size_t kb = (size_t)k0 * 2;
    gload_lds16(aG0 + kb, aL0);
    gload_lds16(aG1 + kb, aL1);
    gload_lds16(bG0 + kb, bL0);
    gload_lds16(bG1 + kb, bL1);
    __syncthreads();
    bf16x8 af[4], bfv[4];
#pragma unroll
    for (int r = 0; r < 4; r++)
      af[r] = *(const bf16x8*)(a_lds + (wr * 64 + r * 16 + c16) * 32 + quad * 8);
#pragma unroll
    for (int c = 0; c < 4; c++)
      bfv[c] = *(const bf16x8*)(b_lds + (wc * 64 + c * 16 + c16) * 32 + quad * 8);
#pragma unroll
    for (int r = 0; r < 4; r++)
#pragma unroll
      for (int c = 0; c < 4; c++)
        acc[r][c] = __builtin_amdgcn_mfma_f32_16x16x32_bf16(af[r], bfv[c], acc[r][c], 0, 0, 0);
  }

#pragma unroll
  for (int r = 0; r < 4; r++)
#pragma unroll
    for (int c = 0; c < 4; c++)
#pragma unroll
      for (int rr = 0; rr < 4; rr++) {
        int m = m0 + wr * 64 + r * 16 + quad * 4 + rr;
        int n = n0 + wc * 64 + c * 16 + c16;
        float val = acc[r][c][rr];
        if (OUT_BF16) ((bf16*)Cout)[(size_t)m * N + n] = __float2bfloat16(val);
        else          ((float*)Cout)[(size_t)m * N + n] = val;
      }
}

// ================= 256x256 8-phase GEMM, v3: m201-faithful fine interleave =================
// Per phase: {ds-read subtile ∥ stage 1 half-tile ∥ 16 MFMA}. Quadrant order Q00,Q10,Q01,Q11
// per K-tile so reads are 12,8,4,0 (minimum given deps) and EVERY phase carries a stage:
//   ph1: ds A0-3+B01(buf0), stage (t+1)B0, Q00   ph5: ds A0-3+B01(buf1), stage (t+2)B0, Q00
//   ph2: ds A4-7(buf0),     stage (t+1)B1, Q10   ph6: ds A4-7(buf1),     stage (t+2)B1, Q10
//   ph3: ds B23(buf0),      stage (t+2)A0, Q01   ph7: ds B23(buf1),      stage (t+3)A0, Q01
//   ph4: --,                stage (t+2)A1, Q11   ph8: --,                stage (t+3)A1, Q11
//   vmcnt(4) at end ph4/ph8 (before barrier): 8 oldest loads == tile read next, exactly.
// Region ledger (all verified): buf0.A reads end ph2 -> stage ph3/4; buf0.B reads end ph3
// -> stage ph5/6; buf1.A reads end ph6 -> stage ph7/8; buf1.B reads end ph7 -> stage ph1/2
// of next iter. vmcnt->barrier makes per-wave drains cross-wave sound.
#define BARX() asm volatile("s_barrier" ::: "memory")
#define LGKM0() { asm volatile("s_waitcnt lgkmcnt(0)" ::: "memory"); __builtin_amdgcn_sched_barrier(0); }
#define VMW4() asm volatile("s_waitcnt vmcnt(4)" ::: "memory")
#define VMW0() asm volatile("s_waitcnt vmcnt(0)" ::: "memory")
#define PRIO1 __builtin_amdgcn_s_setprio(1)
#define PRIO0 __builtin_amdgcn_s_setprio(0)

// 16 MFMA: acc[MB+mf][NB+nf] over mf 0..3, nf 0..1, kk 0..1
#define QUADQ(MB, NB)                                                              \
  { _Pragma("unroll") for (int kk_ = 0; kk_ < 2; ++kk_)                            \
    _Pragma("unroll") for (int mf_ = 0; mf_ < 4; ++mf_)                            \
    _Pragma("unroll") for (int nf_ = 0; nf_ < 2; ++nf_)                            \
      acc[(MB) + mf_][(NB) + nf_] = __builtin_amdgcn_mfma_f32_16x16x32_bf16(       \
          ar[(MB) + mf_][kk_], br[(NB) + nf_][kk_],                                \
          acc[(MB) + mf_][(NB) + nf_], 0, 0, 0); }

__global__ __launch_bounds__(512, 2) void k_gemm8(const bf16* __restrict__ A, const bf16* __restrict__ BT,
                                                  bf16* __restrict__ O0, bf16* __restrict__ O1,
                                                  int nsplit, int M, int Ntot, int K) {
  extern __shared__ char lds[];
  const int tid = threadIdx.x;
  const int lane = tid & 63;
  const int w = tid >> 6;        // 0..7
  const int wr = w >> 2;         // 0..1 (M half)
  const int wc = w & 3;          // 0..3 (N quarter)
  const int quad = lane >> 4, c16 = lane & 15;
  const int m0 = blockIdx.y * 256, n0 = blockIdx.x * 256;

  const int srow = (w << 4) | (lane >> 3);
  const int gsw = (((lane & 7) ^ (lane >> 3)) << 4);   // inverse-swizzled source granule
  const size_t rowBytes = (size_t)K * 2;
  const char* aS = (const char*)(A + (size_t)(m0 + srow) * K) + gsw;
  const char* bS = (const char*)(BT + (size_t)(n0 + srow) * K) + gsw;

  auto stage = [&](int matB, int buf, int h, int t) {
    const char* base = (matB ? bS : aS) + (size_t)h * 128 * rowBytes + (size_t)t * 128;
    char* ldst = lds + buf * 65536 + matB * 32768 + h * 16384 + w * 2048;
    gload_lds16(base, ldst);
    gload_lds16(base + 8 * rowBytes, ldst + 1024);
  };
  auto ldA = [&](int buf, int mf, int kk) -> bf16x8 {
    int row = wr * 128 + mf * 16 + c16;
    return *(const bf16x8*)(lds + buf * 65536 + row * 128 + ((((kk << 2) | quad) ^ (c16 & 7)) << 4));
  };
  auto ldB = [&](int buf, int nf, int kk) -> bf16x8 {
    int row = wc * 64 + nf * 16 + c16;
    return *(const bf16x8*)(lds + buf * 65536 + 32768 + row * 128 + ((((kk << 2) | quad) ^ (c16 & 7)) << 4));
  };

  f32x4 acc[8][4];
  const f32x4 fz = {0.f, 0.f, 0.f, 0.f};
#pragma unroll
  for (int i = 0; i < 8; i++)
#pragma unroll
    for (int j = 0; j < 4; j++) acc[i][j] = fz;
  bf16x8 ar[8][2], br[4][2];

  const int nT = K >> 6;
  const int nIter = nT >> 1;

  // prologue: tile0 full + tile1 A -> 12 loads; vmcnt(4) leaves t1.A in flight (steady entry)
  stage(0, 0, 0, 0); stage(0, 0, 1, 0);
  stage(1, 0, 0, 0); stage(1, 0, 1, 0);
  stage(0, 1, 0, 1); stage(0, 1, 1, 1);
  VMW4();
  BARX();

  for (int it = 0; it < nIter; ++it) {
    const int t = it * 2;
    const bool last = (it == nIter - 1);
    // ---- ph1: ds A0-3 + B01 (buf0); stage (t+1)B0; Q00 ----
#pragma unroll
    for (int mf = 0; mf < 4; ++mf) { ar[mf][0] = ldA(0, mf, 0); ar[mf][1] = ldA(0, mf, 1); }
#pragma unroll
    for (int nf = 0; nf < 2; ++nf) { br[nf][0] = ldB(0, nf, 0); br[nf][1] = ldB(0, nf, 1); }
    stage(1, 1, 0, t + 1);
    BARX(); LGKM0();
    PRIO1; QUADQ(0, 0); PRIO0;
    BARX();
    // ---- ph2: ds A4-7 (buf0); stage (t+1)B1; Q10 ----
#pragma unroll
    for (int mf = 4; mf < 8; ++mf) { ar[mf][0] = ldA(0, mf, 0); ar[mf][1] = ldA(0, mf, 1); }
    stage(1, 1, 1, t + 1);
    BARX(); LGKM0();
    PRIO1; QUADQ(4, 0); PRIO0;
    BARX();
    // ---- ph3: ds B23 (buf0); stage (t+2)A0; Q01 ----
#pragma unroll
    for (int nf = 2; nf < 4; ++nf) { br[nf][0] = ldB(0, nf, 0); br[nf][1] = ldB(0, nf, 1); }
    if (!last) stage(0, 0, 0, t + 2);
    BARX(); LGKM0();
    PRIO1; QUADQ(0, 2); PRIO0;
    BARX();
    // ---- ph4: stage (t+2)A1; Q11; counted wait -> tile t+1 fully landed ----
    if (!last) stage(0, 0, 1, t + 2);
    BARX();
    PRIO1; QUADQ(4, 2); PRIO0;
    if (!last) { VMW4(); } else { VMW0(); }
    BARX();
    // ---- ph5: ds A0-3 + B01 (buf1); stage (t+2)B0; Q00 ----
#pragma unroll
    for (int mf = 0; mf < 4; ++mf) { ar[mf][0] = ldA(1, mf, 0); ar[mf][1] = ldA(1, mf, 1); }
#pragma unroll
    for (int nf = 0; nf < 2; ++nf) { br[nf][0] = ldB(1, nf, 0); br[nf][1] = ldB(1, nf, 1); }
    if (!last) stage(1, 0, 0, t + 2);
    BARX(); LGKM0();
    PRIO1; QUADQ(0, 0); PRIO0;
    BARX();
    // ---- ph6: ds A4-7 (buf1); stage (t+2)B1; Q10 ----
#pragma unroll
    for (int mf = 4; mf < 8; ++mf) { ar[mf][0] = ldA(1, mf, 0); ar[mf][1] = ldA(1, mf, 1); }
    if (!last) stage(1, 0, 1, t + 2);
    BARX(); LGKM0();
    PRIO1; QUADQ(4, 0); PRIO0;
    BARX();
    // ---- ph7: ds B23 (buf1); stage (t+3)A0; Q01 ----
#pragma unroll
    for (int nf = 2; nf < 4; ++nf) { br[nf][0] = ldB(1, nf, 0); br[nf][1] = ldB(1, nf, 1); }
    if (!last) stage(0, 1, 0, t + 3);
    BARX(); LGKM0();
    PRIO1; QUADQ(0, 2); PRIO0;
    BARX();
    // ---- ph8: stage (t+3)A1; Q11; counted wait -> tile t+2 fully landed ----
    if (!last) stage(0, 1, 1, t + 3);
    BARX();
    PRIO1; QUADQ(4, 2); PRIO0;
    if (!last) VMW4();
    BARX();
  }

  // epilogue: whole block routes to one output (BN=256 divides nsplit)
  bf16* Ob; int ldo, nc0;
  if (n0 < nsplit) { Ob = O0; ldo = nsplit; nc0 = n0; }
  else             { Ob = O1; ldo = Ntot - nsplit; nc0 = n0 - nsplit; }
#pragma unroll
  for (int mf = 0; mf < 8; ++mf)
#pragma unroll
    for (int nf = 0; nf < 4; ++nf)
#pragma unroll
      for (int rr = 0; rr < 4; ++rr) {
        int m = m0 + wr * 128 + mf * 16 + quad * 4 + rr;
        int n = nc0 + wc * 64 + nf * 16 + c16;
        Ob[(size_t)m * ldo + n] = __float2bfloat16(acc[mf][nf][rr]);
      }
}

// ---------------- Retention v4: rotated loop {PV(t-1); S(t)}, K-dbuf + V-sbuf + P-dbuf ----
// (unchanged from R4 — improved there; see that round's ledger)
__global__ __launch_bounds__(256, 2) void k_retention(const bf16* __restrict__ q, const bf16* __restrict__ k,
                                                      const char* __restrict__ vS, const bf16* __restrict__ g,
                                                      const float* __restrict__ gnw, bf16* __restrict__ X) {
  extern __shared__ char smem[];
  float* red = (float*)(smem + 75776);
  bf16* o_lds = (bf16*)smem;   // epilogue alias (64KB)

  const int tid = threadIdx.x;
  const int l = tid & 63, w = tid >> 6;
  const int quad = l >> 4, c16 = l & 15;

  const int bid = blockIdx.x;
  const int u = (bid & 255) >> 4;
  const int qt = (bid < 256) ? (31 - u) : u;   // heavy half then light half
  const int bh = bid & 15;
  const int b = bh >> 3, h = bh & 7;
  const int q0 = qt * 64;

  bf16x8 qf[8];
  {
    const bf16* qrow = q + ((size_t)(b * Tn + q0 + w * 16 + c16) * NH + h) * DKk + quad * 8;
#pragma unroll
    for (int c = 0; c < 8; c++) qf[c] = *(const bf16x8*)(qrow + c * 32);
  }

  const float log2g = log2f(1.0f - exp2f(-5.0f - (float)h));

  f32x4 acc[4][8];
  const f32x4 fz = {0.f, 0.f, 0.f, 0.f};
#pragma unroll
  for (int rt = 0; rt < 4; rt++)
#pragma unroll
    for (int n = 0; n < 8; n++) acc[rt][n] = fz;

  const int ktmax = 2 * qt + 1;
  const float Dcut = 30.0f / (-log2g);
  int kt0 = (int)fmaxf(0.0f, floorf(((float)q0 - Dcut) * (1.0f / 32.0f)));

  const char* vS_tilebase = vS + (size_t)(bh * 64) * 32768;

  auto stageK = [&](int kt) {
    const int pb = (kt - kt0) & 1;
#pragma unroll
    for (int i = 0; i < 4; i++) {
      int instr = w * 4 + i;
      int j = instr * 2 + (l >> 5);
      int cg = (l & 31) ^ (j & 7);
      const char* gp = (const char*)(k + ((size_t)(b * Tn + kt * 32 + j) * NH + h) * DKk) + cg * 16;
      gload_lds16(gp, smem + pb * 16384 + instr * 1024);
    }
  };
  auto stageV = [&](int kt) {
#pragma unroll
    for (int i = 0; i < 8; i++) {
      int instr = w * 8 + i;
      const char* gp = vS_tilebase + (size_t)kt * 32768 + instr * 1024 + l * 16;
      gload_lds16(gp, smem + 32768 + instr * 1024);
    }
  };

  auto S_phase = [&](int kt) {
    const int pb = (kt - kt0) & 1;
    f32x4 sacc[2] = {fz, fz};
#pragma unroll
    for (int jt = 0; jt < 2; jt++)
#pragma unroll
      for (int c = 0; c < 8; c++) {
        const char* kp = smem + pb * 16384 + (jt * 16 + c16) * 512 + (((c * 4 + quad) ^ (c16 & 7)) * 16);
        bf16x8 bfrag = *(const bf16x8*)kp;
        sacc[jt] = __builtin_amdgcn_mfma_f32_16x16x32_bf16(qf[c], bfrag, sacc[jt], 0, 0, 0);
      }
    ushort_t* pbuf = (ushort_t*)(smem + 65536 + pb * 5120);
#pragma unroll
    for (int jt = 0; jt < 2; jt++)
#pragma unroll
      for (int r = 0; r < 4; r++) {
        int ig = q0 + w * 16 + quad * 4 + r;
        int jg = kt * 32 + jt * 16 + c16;
        int d = ig - jg;
        float val = (d >= 0) ? sacc[jt][r] * exp2f(log2g * (float)d) : 0.0f;
        pbuf[(w * 16 + quad * 4 + r) * 40 + jt * 16 + c16] = f2bf_raw(val);
      }
  };

  auto PV_phase = [&](int kt) {
    const int pb = (kt - kt0) & 1;
    const char* pbuf = smem + 65536 + pb * 5120;
    bf16x8 pa[4];
#pragma unroll
    for (int rt = 0; rt < 4; rt++)
      pa[rt] = *(const bf16x8*)(pbuf + (rt * 16 + c16) * 80 + quad * 16);
    const char* v_lds = smem + 32768;
#pragma unroll
    for (int n = 0; n < 8; n++) {
      bf16x8 bv = *(const bf16x8*)(v_lds + quad * 8192 + (w * 128 + n * 16 + c16) * 16);
#pragma unroll
      for (int rt = 0; rt < 4; rt++)
        acc[rt][n] = __builtin_amdgcn_mfma_f32_16x16x32_bf16(pa[rt], bv, acc[rt][n], 0, 0, 0);
    }
  };

#define SBAR() { __builtin_amdgcn_sched_barrier(0); __builtin_amdgcn_s_barrier(); }
#define WLGKM0() { asm volatile("s_waitcnt lgkmcnt(0)" ::: "memory"); }

  // ---- peeled first iteration (S-only) ----
  stageK(kt0);                                        // out: K(kt0)(4)  [+qf(8) older]
  stageV(kt0);                                        // out: +V(kt0)(8)
  asm volatile("s_waitcnt vmcnt(8)" ::: "memory");    // drains qf + K(kt0); V(kt0) flies
  SBAR();
  S_phase(kt0);
  if (kt0 + 1 <= ktmax) stageK(kt0 + 1);              // out: V(kt0)(8), K(kt0+1)(4)
  WLGKM0(); SBAR();

  // ---- main loop ----
  for (int kt = kt0 + 1; kt <= ktmax; ++kt) {
    asm volatile("s_waitcnt vmcnt(4)" ::: "memory");  // V(kt-1) landed; K(kt) flies
    SBAR();
    PV_phase(kt - 1);
    WLGKM0(); SBAR();                                 // V buf + p[kt-1] free
    stageV(kt);                                       // out: K(kt)(4), V(kt)(8)
    asm volatile("s_waitcnt vmcnt(8)" ::: "memory");  // K(kt) landed; V(kt) flies
    SBAR();
    S_phase(kt);
    if (kt + 1 <= ktmax) stageK(kt + 1);              // out: V(kt)(8), K(kt+1)(4)
    WLGKM0(); SBAR();                                 // p[kt] visible
  }

  // ---- epilogue PV(ktmax) ----
  asm volatile("s_waitcnt vmcnt(0)" ::: "memory");
  SBAR();
  PV_phase(ktmax);

  // RMS: wave has 128-dv partial for all 64 rows -> cross-wave combine via red
  __syncthreads();
#pragma unroll
  for (int rt = 0; rt < 4; rt++)
#pragma unroll
    for (int r = 0; r < 4; r++) {
      float s = 0.f;
#pragma unroll
      for (int n = 0; n < 8; n++) { float v = acc[rt][n][r]; s += v * v; }
      s += __shfl_xor(s, 1);
      s += __shfl_xor(s, 2);
      s += __shfl_xor(s, 4);
      s += __shfl_xor(s, 8);
      if (c16 == 0) red[(rt * 16 + quad * 4 + r) * 4 + w] = s;
    }
  __syncthreads();
  float ss[4][4];
#pragma unroll
  for (int rt = 0; rt < 4; rt++)
#pragma unroll
    for (int r = 0; r < 4; r++) {
      int row = rt * 16 + quad * 4 + r;
      float tot = red[row * 4] + red[row * 4 + 1] + red[row * 4 + 2] + red[row * 4 + 3];
      ss[rt][r] = rsqrtf(tot * (1.0f / DVv) + EPSf);
    }
  __syncthreads();

#pragma unroll
  for (int n = 0; n < 8; n++) {
    int col = w * 128 + n * 16 + c16;
    float gw = gnw[col];
#pragma unroll
    for (int rt = 0; rt < 4; rt++)
#pragma unroll
      for (int r = 0; r < 4; r++) {
        int row = rt * 16 + quad * 4 + r;
        o_lds[row * 512 + col] = __float2bfloat16(acc[rt][n][r] * ss[rt][r] * gw);
      }
  }
  __syncthreads();

#pragma unroll
  for (int it = 0; it < 16; it++) {
    int cid = it * 256 + tid;
    int row = cid >> 6;
    int cp = (cid & 63) * 8;
    const ushort_t* gp = (const ushort_t*)g + ((size_t)(b * Tn + q0 + row) * NH + h) * DVv + cp;
    us8 gv = *(const us8*)gp;
    us8 ov;
#pragma unroll
    for (int e = 0; e < 8; e++) {
      float gf = bf2f_raw(gv[e]);
      float gate = gf / (1.0f + expf(-gf));
      float of = __bfloat162float(o_lds[row * 512 + cp + e]);
      ov[e] = f2bf_raw(of * gate);
    }
    *(us8*)((ushort_t*)X + ((size_t)(b * Tn + q0 + row) * NH + h) * DVv + cp) = ov;
  }
}

extern "C" void kernel_launch(void* const* d_in, const int* in_sizes, int n_in,
                              void* d_out, int out_size, void* d_ws, size_t ws_size,
                              hipStream_t stream) {
  const float* hs  = (const float*)d_in[0];
  const float* Wq  = (const float*)d_in[1];
  const float* Wk  = (const float*)d_in[2];
  const float* Wv  = (const float*)d_in[3];
  const float* Wg  = (const float*)d_in[4];
  const float* Wo  = (const float*)d_in[5];
  const float* gnw = (const float*)d_in[6];
  float* out = (float*)d_out;
  char* ws = (char*)d_ws;

  bf16* hsb = (bf16*)(ws);                    // 16 MB
  bf16* WqT = (bf16*)(ws + 16777216);         //  8 MB  } contiguous [4096][2048] for fused qk
  bf16* WkT = (bf16*)(ws + 25165824);         //  8 MB  }
  bf16* WvT = (bf16*)(ws + 33554432);         // 16 MB  } contiguous [8192][2048] for fused vg
  bf16* WgT = (bf16*)(ws + 50331648);         // 16 MB  }
  char* vSb = ws;                              // alias hsb/WqT/WkT (dead after q/k/v/g GEMMs)
  bf16* WoT = (bf16*)(ws + 33554432);         // alias WvT (dead after vg GEMM)
  bf16* qb = (bf16*)(ws + 67108864);          // 16 MB
  bf16* kb = (bf16*)(ws + 83886080);          // 16 MB
  bf16* vb = (bf16*)(ws + 100663296);         // 32 MB
  bf16* gb = (bf16*)(ws + 134217728);         // 32 MB
  bf16* Xb = vb;                               // alias v (dead after vS build)

  static bool attr_done = false;
  if (!attr_done) {
    hipFuncSetAttribute((const void*)k_gemm8, hipFuncAttributeMaxDynamicSharedMemorySize, 131072);
    hipFuncSetAttribute((const void*)k_retention, hipFuncAttributeMaxDynamicSharedMemorySize, 76800);
    attr_done = true;
  }

  dim3 tb(32, 8);

  k_f32_to_bf16<<<8192, 256, 0, stream>>>((const float4*)hs, (ushort4*)hsb, 2097152);
  k_transpose_w<<<dim3(HID / 32, HID / 32), tb, 0, stream>>>(Wq, WqT, HID, HID);
  k_transpose_w<<<dim3(HID / 32, HID / 32), tb, 0, stream>>>(Wk, WkT, HID, HID);
  k_transpose_w<<<dim3(NH * DVv / 32, HID / 32), tb, 0, stream>>>(Wv, WvT, HID, NH * DVv);
  k_transpose_w<<<dim3(NH * DVv / 32, HID / 32), tb, 0, stream>>>(Wg, WgT, HID, NH * DVv);
  // fused q|k: C[4096][4096] = hsb @ [WqT|WkT]^T, split at n=2048 -> qb, kb
  k_gemm8<<<dim3(16, 16), 512, 131072, stream>>>(hsb, WqT, qb, kb, 2048, 4096, 4096, 2048);
  // fused v|g: C[4096][8192] = hsb @ [WvT|WgT]^T, split at n=4096 -> vb, gb
  k_gemm8<<<dim3(32, 16), 512, 131072, stream>>>(hsb, WvT, vb, gb, 4096, 4096, 8192, 2048);
  k_rope<<<16384, 256, 0, stream>>>(qb, 0.0625f);
  k_rope<<<16384, 256, 0, stream>>>(kb, 1.0f);
  k_build_vS<<<dim3(64, 16), 256, 0, stream>>>((const ushort_t*)vb, (ushort_t*)vSb);
  k_transpose_w<<<dim3(HID / 32, NH * DVv / 32), tb, 0, stream>>>(Wo, WoT, NH * DVv, HID);
  k_retention<<<512, 256, 76800, stream>>>(qb, kb, vSb, gb, gnw, Xb);
  k_gemm<false><<<dim3(16, 32), 256, 0, stream>>>(Xb, WoT, out, 4096, 2048, 4096);
}